// Round 1
// baseline (4815.390 us; speedup 1.0000x reference)
//
#include <hip/hip_runtime.h>
#include <hip/hip_bf16.h>
#include <math.h>

#define B_   2
#define S_   2048
#define HID_ 1024
#define H_   16
#define D_   64

// ---------------- GEMM f32: Y = A(MxK) @ W(KxN), row-major ----------------
#define BM 128
#define BN 64
#define BK 16

__global__ __launch_bounds__(256) void gemm_f32(const float* __restrict__ A,
                                                const float* __restrict__ W,
                                                float* __restrict__ Y,
                                                int M, int N, int K) {
    __shared__ float As[BK][BM + 4];   // row stride 132 floats = 528B, 16B-aligned rows
    __shared__ float Bs[BK][BN + 4];   // row stride 68 floats
    const int t  = threadIdx.x;
    const int m0 = blockIdx.y * BM;
    const int n0 = blockIdx.x * BN;
    const int tm = (t >> 4) << 3;      // 0..120 step 8
    const int tn = (t & 15) << 2;      // 0..60 step 4
    const int ar = t >> 4, ac = t & 15;   // A staging: 16 rows x 16 k-cols per pass
    const int br = t >> 6, bc = t & 63;   // B staging: 4 k-rows x 64 n-cols per pass
    float acc[8][4] = {};
    for (int k0 = 0; k0 < K; k0 += BK) {
        #pragma unroll
        for (int i = 0; i < 8; i++)
            As[ac][ar + i * 16] = A[(long)(m0 + ar + i * 16) * K + k0 + ac];
        #pragma unroll
        for (int i = 0; i < 4; i++)
            Bs[br + i * 4][bc] = W[(long)(k0 + br + i * 4) * N + n0 + bc];
        __syncthreads();
        #pragma unroll
        for (int kk = 0; kk < BK; kk++) {
            float4 alo = *(const float4*)&As[kk][tm];
            float4 ahi = *(const float4*)&As[kk][tm + 4];
            float4 b4  = *(const float4*)&Bs[kk][tn];
            float a[8] = {alo.x, alo.y, alo.z, alo.w, ahi.x, ahi.y, ahi.z, ahi.w};
            float b[4] = {b4.x, b4.y, b4.z, b4.w};
            #pragma unroll
            for (int i = 0; i < 8; i++)
                #pragma unroll
                for (int j = 0; j < 4; j++)
                    acc[i][j] += a[i] * b[j];
        }
        __syncthreads();
    }
    #pragma unroll
    for (int i = 0; i < 8; i++) {
        float4 r;
        r.x = acc[i][0]; r.y = acc[i][1]; r.z = acc[i][2]; r.w = acc[i][3];
        *(float4*)&Y[(long)(m0 + tm + i) * N + n0 + tn] = r;
    }
}

// ---------------- RoPE in place on q and k ----------------
// q' [d]    = q[d]*cos[d]    - q[d+32]*sin[d]       (d < 32)
// q' [d+32] = q[d+32]*cos[d+32] + q[d]*sin[d+32]
__global__ __launch_bounds__(256) void rope_qk(float* __restrict__ q, float* __restrict__ k,
                                               const float* __restrict__ cosb,
                                               const float* __restrict__ sinb) {
    int tid = blockIdx.x * 256 + threadIdx.x;       // B*S*H*32 threads
    int d = tid & 31;
    int h = (tid >> 5) & (H_ - 1);
    int s = (tid >> 9) & (S_ - 1);
    int b = tid >> 20;
    long base = ((long)(b * S_ + s) * H_ + h) * D_;
    float c0 = cosb[s * D_ + d], c1 = cosb[s * D_ + d + 32];
    float s0 = sinb[s * D_ + d], s1 = sinb[s * D_ + d + 32];
    float q0 = q[base + d], q1 = q[base + d + 32];
    q[base + d]      = q0 * c0 - q1 * s0;
    q[base + d + 32] = q1 * c1 + q0 * s1;
    float k0 = k[base + d], k1 = k[base + d + 32];
    k[base + d]      = k0 * c0 - k1 * s0;
    k[base + d + 32] = k1 * c1 + k0 * s1;
}

// ---------------- Flash attention, 1 wave per (b, h, 64 q-rows) ----------------
__global__ __launch_bounds__(64) void attn_f32(const float* __restrict__ q,
                                               const float* __restrict__ k,
                                               const float* __restrict__ v,
                                               const float* __restrict__ rel_bias,
                                               float* __restrict__ ctx) {
    __shared__ float kT[64 * 64];
    __shared__ float vT[64 * 64];
    __shared__ float sL[64 * 64];
    __shared__ float bb[128];
    const int lane = threadIdx.x;
    const int qt = blockIdx.x, h = blockIdx.y, b = blockIdx.z;
    const int q0 = qt * 64;
    const int qi = q0 + lane;

    const float* qrow = q + ((long)(b * S_ + qi) * H_ + h) * D_;
    float qreg[64];
    #pragma unroll
    for (int i = 0; i < 16; i++) {
        float4 f = ((const float4*)qrow)[i];
        qreg[4 * i + 0] = f.x; qreg[4 * i + 1] = f.y;
        qreg[4 * i + 2] = f.z; qreg[4 * i + 3] = f.w;
    }
    float o[64];
    #pragma unroll
    for (int d = 0; d < 64; d++) o[d] = 0.f;
    float m = -1.0e30f, l = 0.f;

    const float inv_log8 = 1.0f / logf(8.0f);

    for (int kt = 0; kt <= qt; kt++) {
        const int k0 = kt * 64;
        // ---- stage K, V tiles (coalesced: 4 rows x 16 float4-lanes per pass) ----
        #pragma unroll
        for (int p = 0; p < 16; p++) {
            int r = p * 4 + (lane >> 4);
            int c = (lane & 15) * 4;
            long g = ((long)(b * S_ + k0 + r) * H_ + h) * D_ + c;
            *(float4*)&kT[r * 64 + c] = *(const float4*)&k[g];
            *(float4*)&vT[r * 64 + c] = *(const float4*)&v[g];
        }
        // ---- stage bias row: bb[i] = bias(rp = q0-k0-63+i, h) ----
        {
            int base_rp = q0 - k0 - 63;
            #pragma unroll
            for (int u = 0; u < 2; u++) {
                int i = lane + u * 64;
                int rp = base_rp + i;
                float bv = 0.f;
                if (rp >= 0 && rp < S_) {
                    int bucket;
                    if (rp < 16) bucket = rp;
                    else {
                        int lg = (int)(logf((float)rp * 0.0625f) * inv_log8 * 16.0f);
                        bucket = 16 + lg;
                        if (bucket > 31) bucket = 31;
                    }
                    bv = rel_bias[bucket * H_ + h];
                }
                bb[i] = bv;
            }
        }
        __syncthreads();

        // ---- scores: s[j] = q.k/8 + bias, causal mask; track tile max ----
        float tmax = -1.0e30f;
        #pragma unroll 4
        for (int j = 0; j < 64; j++) {
            float acc0 = 0.f, acc1 = 0.f;
            #pragma unroll
            for (int d8 = 0; d8 < 8; d8++) {
                float4 ka = *(const float4*)&kT[j * 64 + d8 * 8];
                float4 kb = *(const float4*)&kT[j * 64 + d8 * 8 + 4];
                acc0 += qreg[d8*8+0]*ka.x + qreg[d8*8+1]*ka.y + qreg[d8*8+2]*ka.z + qreg[d8*8+3]*ka.w;
                acc1 += qreg[d8*8+4]*kb.x + qreg[d8*8+5]*kb.y + qreg[d8*8+6]*kb.z + qreg[d8*8+7]*kb.w;
            }
            int kj = k0 + j;
            float sc = (acc0 + acc1) * 0.125f + bb[lane - j + 63];
            float sv = (kj <= qi) ? sc : -1.0e9f;
            sL[j * 64 + lane] = sv;
            tmax = fmaxf(tmax, sv);
        }
        // ---- online softmax update + PV ----
        float mnew = fmaxf(m, tmax);
        float scale = __expf(m - mnew);
        l *= scale;
        #pragma unroll
        for (int d = 0; d < 64; d++) o[d] *= scale;
        #pragma unroll 2
        for (int j = 0; j < 64; j++) {
            float p = __expf(sL[j * 64 + lane] - mnew);
            l += p;
            #pragma unroll
            for (int d4 = 0; d4 < 16; d4++) {
                float4 v4 = *(const float4*)&vT[j * 64 + d4 * 4];
                o[d4*4+0] += p * v4.x; o[d4*4+1] += p * v4.y;
                o[d4*4+2] += p * v4.z; o[d4*4+3] += p * v4.w;
            }
        }
        m = mnew;
        __syncthreads();
    }
    float rinv = 1.0f / l;
    float* orow = ctx + (long)(b * S_ + qi) * HID_ + h * D_;
    #pragma unroll
    for (int i = 0; i < 16; i++) {
        float4 f;
        f.x = o[4*i+0]*rinv; f.y = o[4*i+1]*rinv;
        f.z = o[4*i+2]*rinv; f.w = o[4*i+3]*rinv;
        ((float4*)orow)[i] = f;
    }
}

extern "C" void kernel_launch(void* const* d_in, const int* in_sizes, int n_in,
                              void* d_out, int out_size, void* d_ws, size_t ws_size,
                              hipStream_t stream) {
    const float* x    = (const float*)d_in[0];
    const float* Wq   = (const float*)d_in[1];
    const float* Wk   = (const float*)d_in[2];
    const float* Wv   = (const float*)d_in[3];
    const float* Wo   = (const float*)d_in[4];
    const float* rb   = (const float*)d_in[5];
    const float* cosb = (const float*)d_in[6];
    const float* sinb = (const float*)d_in[7];
    float* out = (float*)d_out;

    float* ws  = (float*)d_ws;
    float* q   = ws;                 // 4M floats
    float* k   = ws + 4194304;       // 4M
    float* v   = ws + 8388608;       // 4M
    float* ctx = ws + 12582912;      // 4M  -> exactly 64 MB total

    const int M = B_ * S_;           // 4096
    dim3 blk(256);
    dim3 ggrid(HID_ / BN, M / BM);   // (16, 32)

    hipLaunchKernelGGL(gemm_f32, ggrid, blk, 0, stream, x, Wq, q, M, HID_, HID_);
    hipLaunchKernelGGL(gemm_f32, ggrid, blk, 0, stream, x, Wk, k, M, HID_, HID_);
    hipLaunchKernelGGL(gemm_f32, ggrid, blk, 0, stream, x, Wv, v, M, HID_, HID_);
    hipLaunchKernelGGL(rope_qk, dim3((B_ * S_ * H_ * 32) / 256), blk, 0, stream,
                       q, k, cosb, sinb);
    hipLaunchKernelGGL(attn_f32, dim3(S_ / 64, H_, B_), dim3(64), 0, stream,
                       q, k, v, rb, ctx);
    hipLaunchKernelGGL(gemm_f32, ggrid, blk, 0, stream, ctx, Wo, out, M, HID_, HID_);
}

// Round 2
// 760.951 us; speedup vs baseline: 6.3281x; 6.3281x over previous
//
#include <hip/hip_runtime.h>
#include <hip/hip_bf16.h>
#include <math.h>

#define B_   2
#define S_   2048
#define HID_ 1024
#define H_   16
#define D_   64

typedef __attribute__((ext_vector_type(8))) short bf16x8;
typedef __attribute__((ext_vector_type(4))) float f32x4;

// ---------------- GEMM f32: Y = A(MxK) @ W(KxN), row-major ----------------
#define BM 128
#define BN 64
#define BK 16

__global__ __launch_bounds__(256) void gemm_f32(const float* __restrict__ A,
                                                const float* __restrict__ W,
                                                float* __restrict__ Y,
                                                int M, int N, int K) {
    __shared__ float As[BK][BM + 4];
    __shared__ float Bs[BK][BN + 4];
    const int t  = threadIdx.x;
    const int m0 = blockIdx.y * BM;
    const int n0 = blockIdx.x * BN;
    const int tm = (t >> 4) << 3;
    const int tn = (t & 15) << 2;
    const int ar = t >> 4, ac = t & 15;
    const int br = t >> 6, bc = t & 63;
    float acc[8][4] = {};
    for (int k0 = 0; k0 < K; k0 += BK) {
        #pragma unroll
        for (int i = 0; i < 8; i++)
            As[ac][ar + i * 16] = A[(long)(m0 + ar + i * 16) * K + k0 + ac];
        #pragma unroll
        for (int i = 0; i < 4; i++)
            Bs[br + i * 4][bc] = W[(long)(k0 + br + i * 4) * N + n0 + bc];
        __syncthreads();
        #pragma unroll
        for (int kk = 0; kk < BK; kk++) {
            float4 alo = *(const float4*)&As[kk][tm];
            float4 ahi = *(const float4*)&As[kk][tm + 4];
            float4 b4  = *(const float4*)&Bs[kk][tn];
            float a[8] = {alo.x, alo.y, alo.z, alo.w, ahi.x, ahi.y, ahi.z, ahi.w};
            float b[4] = {b4.x, b4.y, b4.z, b4.w};
            #pragma unroll
            for (int i = 0; i < 8; i++)
                #pragma unroll
                for (int j = 0; j < 4; j++)
                    acc[i][j] += a[i] * b[j];
        }
        __syncthreads();
    }
    #pragma unroll
    for (int i = 0; i < 8; i++) {
        float4 r;
        r.x = acc[i][0]; r.y = acc[i][1]; r.z = acc[i][2]; r.w = acc[i][3];
        *(float4*)&Y[(long)(m0 + tm + i) * N + n0 + tn] = r;
    }
}

// ---------------- RoPE in place on q and k ----------------
__global__ __launch_bounds__(256) void rope_qk(float* __restrict__ q, float* __restrict__ k,
                                               const float* __restrict__ cosb,
                                               const float* __restrict__ sinb) {
    int tid = blockIdx.x * 256 + threadIdx.x;
    int d = tid & 31;
    int h = (tid >> 5) & (H_ - 1);
    int s = (tid >> 9) & (S_ - 1);
    int b = tid >> 20;
    long base = ((long)(b * S_ + s) * H_ + h) * D_;
    float c0 = cosb[s * D_ + d], c1 = cosb[s * D_ + d + 32];
    float s0 = sinb[s * D_ + d], s1 = sinb[s * D_ + d + 32];
    float q0 = q[base + d], q1 = q[base + d + 32];
    q[base + d]      = q0 * c0 - q1 * s0;
    q[base + d + 32] = q1 * c1 + q0 * s1;
    float k0 = k[base + d], k1 = k[base + d + 32];
    k[base + d]      = k0 * c0 - k1 * s0;
    k[base + d + 32] = k1 * c1 + k0 * s1;
}

// ---------------- MFMA flash attention ----------------
// Block = 4 waves, 64 q-rows for one (b,h). Wave w owns q rows [q0+16w, q0+16w+16).
// QK^T computed swapped (A=K, B=Q) so per-q softmax reduce is shfl_xor(16/32).
// P restaged via per-wave LDS; V staged transposed [d][k]; all tiles XOR-swizzled.

static __device__ inline unsigned short f2bf(float f) {
    unsigned u = __builtin_bit_cast(unsigned, f);
    u += 0x7fffu + ((u >> 16) & 1u);          // RNE
    return (unsigned short)(u >> 16);
}
static __device__ inline int swz(int row, int colbytes) {
    return row * 128 + (colbytes ^ ((row & 7) << 4));
}

__global__ __launch_bounds__(256) void attn_mfma(const float* __restrict__ q,
                                                 const float* __restrict__ k,
                                                 const float* __restrict__ v,
                                                 const float* __restrict__ rel_bias,
                                                 float* __restrict__ ctx) {
    __shared__ __align__(16) unsigned char kS[64 * 128];      // K tile [k][d] bf16
    __shared__ __align__(16) unsigned char vT[64 * 128];      // V tile transposed [d][k] bf16
    __shared__ __align__(16) unsigned char pS[4 * 16 * 128];  // per-wave P [q][k] bf16
    __shared__ float bb[128];

    const int t    = threadIdx.x;
    const int lane = t & 63;
    const int w    = t >> 6;
    const int qt = blockIdx.x, h = blockIdx.y, b = blockIdx.z;
    const int q0 = qt * 64;
    const int wq = w * 16;
    const int qlane = lane & 15;   // q col for QK output; also generic row idx
    const int grp   = lane >> 4;   // lane group 0..3

    // ---- Q fragments (B-operand): lane holds Q[q0+wq+qlane][ds*32 + grp*8 + j] ----
    bf16x8 qf[2];
    {
        const float* qrow = q + ((long)(b * S_ + q0 + wq + qlane) * H_ + h) * D_;
        #pragma unroll
        for (int ds_ = 0; ds_ < 2; ds_++) {
            float4 a = ((const float4*)qrow)[ds_ * 8 + grp * 2];
            float4 c = ((const float4*)qrow)[ds_ * 8 + grp * 2 + 1];
            bf16x8 f;
            f[0] = (short)f2bf(a.x); f[1] = (short)f2bf(a.y);
            f[2] = (short)f2bf(a.z); f[3] = (short)f2bf(a.w);
            f[4] = (short)f2bf(c.x); f[5] = (short)f2bf(c.y);
            f[6] = (short)f2bf(c.z); f[7] = (short)f2bf(c.w);
            qf[ds_] = f;
        }
    }

    f32x4 oacc[4];
    #pragma unroll
    for (int db = 0; db < 4; db++) oacc[db] = (f32x4){0.f, 0.f, 0.f, 0.f};
    float m_run = -1.0e30f, l_run = 0.f;

    for (int kt = 0; kt <= qt; kt++) {
        const int k0 = kt * 64;
        // ---- cooperative staging: K -> kS (bf16), V -> vT (bf16, transposed) ----
        #pragma unroll
        for (int i = 0; i < 4; i++) {
            int idx = t + i * 256;
            int r  = idx >> 4;
            int cf = (idx & 15) * 4;
            long g = ((long)(b * S_ + k0 + r) * H_ + h) * D_ + cf;
            float4 k4 = *(const float4*)&k[g];
            float4 v4 = *(const float4*)&v[g];
            ushort4 kp;
            kp.x = f2bf(k4.x); kp.y = f2bf(k4.y); kp.z = f2bf(k4.z); kp.w = f2bf(k4.w);
            *(ushort4*)(kS + swz(r, cf * 2)) = kp;
            *(unsigned short*)(vT + swz(cf + 0, r * 2)) = f2bf(v4.x);
            *(unsigned short*)(vT + swz(cf + 1, r * 2)) = f2bf(v4.y);
            *(unsigned short*)(vT + swz(cf + 2, r * 2)) = f2bf(v4.z);
            *(unsigned short*)(vT + swz(cf + 3, r * 2)) = f2bf(v4.w);
        }
        if (t < 128) {
            int rp = (q0 - k0) + t - 63;
            float bv = 0.f;
            if (rp >= 0) {
                int bucket;
                if (rp < 16) bucket = rp;
                else {
                    int lg = (int)(logf((float)rp * 0.0625f) * 7.69437361f);
                    bucket = 16 + lg;
                    if (bucket > 31) bucket = 31;
                }
                bv = rel_bias[bucket * H_ + h];
            }
            bb[t] = bv;
        }
        __syncthreads();

        // ---- QK^T swapped: sacc[kb][r] = S[k0+kb*16+grp*4+r][q0+wq+qlane] ----
        f32x4 sacc[4];
        #pragma unroll
        for (int kb = 0; kb < 4; kb++) {
            sacc[kb] = (f32x4){0.f, 0.f, 0.f, 0.f};
            #pragma unroll
            for (int ds_ = 0; ds_ < 2; ds_++) {
                bf16x8 kf = *(const bf16x8*)(kS + swz(kb * 16 + qlane, ds_ * 64 + grp * 16));
                sacc[kb] = __builtin_amdgcn_mfma_f32_16x16x32_bf16(kf, qf[ds_], sacc[kb], 0, 0, 0);
            }
        }

        // ---- bias + mask + online softmax (per-q = per lane&15 column) ----
        float pv_[4][4];
        float tmax = -1.0e30f;
        #pragma unroll
        for (int kb = 0; kb < 4; kb++)
            #pragma unroll
            for (int r = 0; r < 4; r++) {
                int k_l = kb * 16 + grp * 4 + r;
                float s = sacc[kb][r] * 0.125f + bb[wq + qlane - k_l + 63];
                s = ((k0 + k_l) <= (q0 + wq + qlane)) ? s : -1.0e9f;
                pv_[kb][r] = s;
                tmax = fmaxf(tmax, s);
            }
        tmax = fmaxf(tmax, __shfl_xor(tmax, 16));
        tmax = fmaxf(tmax, __shfl_xor(tmax, 32));
        float mnew  = fmaxf(m_run, tmax);
        float scale = __expf(m_run - mnew);
        float tsum = 0.f;
        #pragma unroll
        for (int kb = 0; kb < 4; kb++)
            #pragma unroll
            for (int r = 0; r < 4; r++) {
                float p = __expf(pv_[kb][r] - mnew);
                pv_[kb][r] = p;
                tsum += p;
            }
        tsum += __shfl_xor(tsum, 16);
        tsum += __shfl_xor(tsum, 32);
        l_run = l_run * scale + tsum;
        m_run = mnew;

        // ---- P -> pS (bf16), per-wave region ----
        #pragma unroll
        for (int kb = 0; kb < 4; kb++) {
            uint2 u;
            u.x = (unsigned)f2bf(pv_[kb][0]) | ((unsigned)f2bf(pv_[kb][1]) << 16);
            u.y = (unsigned)f2bf(pv_[kb][2]) | ((unsigned)f2bf(pv_[kb][3]) << 16);
            *(uint2*)(pS + w * 2048 + swz(qlane, kb * 32 + grp * 8)) = u;
        }

        // ---- rescale O rows (row q' = grp*4+r needs scale from lane q') ----
        float scl[4];
        #pragma unroll
        for (int r = 0; r < 4; r++) scl[r] = __shfl(scale, grp * 4 + r, 64);
        #pragma unroll
        for (int db = 0; db < 4; db++)
            #pragma unroll
            for (int r = 0; r < 4; r++) oacc[db][r] *= scl[r];

        __builtin_amdgcn_wave_barrier();   // order pS write -> pS read (same wave)

        // ---- PV: O[q][d] += P @ V ----
        bf16x8 pf[2];
        #pragma unroll
        for (int ks = 0; ks < 2; ks++)
            pf[ks] = *(const bf16x8*)(pS + w * 2048 + swz(qlane, ks * 64 + grp * 16));
        #pragma unroll
        for (int db = 0; db < 4; db++)
            #pragma unroll
            for (int ks = 0; ks < 2; ks++) {
                bf16x8 vf = *(const bf16x8*)(vT + swz(db * 16 + qlane, ks * 64 + grp * 16));
                oacc[db] = __builtin_amdgcn_mfma_f32_16x16x32_bf16(pf[ks], vf, oacc[db], 0, 0, 0);
            }
        __syncthreads();
    }

    // ---- epilogue: divide by l, write ctx ----
    float inv = 1.0f / l_run;
    float invr[4];
    #pragma unroll
    for (int r = 0; r < 4; r++) invr[r] = __shfl(inv, grp * 4 + r, 64);
    #pragma unroll
    for (int r = 0; r < 4; r++) {
        long qg = q0 + wq + grp * 4 + r;
        float* dst = ctx + (long)(b * S_ + qg) * HID_ + h * D_ + qlane;
        #pragma unroll
        for (int db = 0; db < 4; db++)
            dst[db * 16] = oacc[db][r] * invr[r];
    }
}

extern "C" void kernel_launch(void* const* d_in, const int* in_sizes, int n_in,
                              void* d_out, int out_size, void* d_ws, size_t ws_size,
                              hipStream_t stream) {
    const float* x    = (const float*)d_in[0];
    const float* Wq   = (const float*)d_in[1];
    const float* Wk   = (const float*)d_in[2];
    const float* Wv   = (const float*)d_in[3];
    const float* Wo   = (const float*)d_in[4];
    const float* rb   = (const float*)d_in[5];
    const float* cosb = (const float*)d_in[6];
    const float* sinb = (const float*)d_in[7];
    float* out = (float*)d_out;

    float* ws  = (float*)d_ws;
    float* q   = ws;
    float* k   = ws + 4194304;
    float* v   = ws + 8388608;
    float* ctx = ws + 12582912;

    const int M = B_ * S_;
    dim3 blk(256);
    dim3 ggrid(HID_ / BN, M / BM);

    hipLaunchKernelGGL(gemm_f32, ggrid, blk, 0, stream, x, Wq, q, M, HID_, HID_);
    hipLaunchKernelGGL(gemm_f32, ggrid, blk, 0, stream, x, Wk, k, M, HID_, HID_);
    hipLaunchKernelGGL(gemm_f32, ggrid, blk, 0, stream, x, Wv, v, M, HID_, HID_);
    hipLaunchKernelGGL(rope_qk, dim3((B_ * S_ * H_ * 32) / 256), blk, 0, stream,
                       q, k, cosb, sinb);
    hipLaunchKernelGGL(attn_mfma, dim3(S_ / 64, H_, B_), blk, 0, stream,
                       q, k, v, rb, ctx);
    hipLaunchKernelGGL(gemm_f32, ggrid, blk, 0, stream, ctx, Wo, out, M, HID_, HID_);
}

// Round 3
// 232.073 us; speedup vs baseline: 20.7495x; 3.2789x over previous
//
#include <hip/hip_runtime.h>
#include <hip/hip_bf16.h>
#include <math.h>

#define B_   2
#define S_   2048
#define HID_ 1024
#define H_   16
#define D_   64

typedef __attribute__((ext_vector_type(8))) short bf16x8;
typedef __attribute__((ext_vector_type(4))) float f32x4;
typedef unsigned short u16;

static __device__ __forceinline__ u16 f2bf(float f) {
    unsigned u = __builtin_bit_cast(unsigned, f);
    u += 0x7fffu + ((u >> 16) & 1u);          // RNE
    return (u16)(u >> 16);
}
static __device__ __forceinline__ int swz(int row, int colbytes) {
    return row * 128 + (colbytes ^ ((row & 7) << 4));
}
static __device__ __forceinline__ void gll16(const void* g, void* l) {
    __builtin_amdgcn_global_load_lds(
        (const __attribute__((address_space(1))) unsigned int*)g,
        (__attribute__((address_space(3))) unsigned int*)l, 16, 0, 0);
}

// ---------------- x (f32) -> bf16 ----------------
__global__ __launch_bounds__(256) void convert_x(const float* __restrict__ in,
                                                 u16* __restrict__ out) {
    int i = blockIdx.x * 256 + threadIdx.x;          // over float4s
    float4 f = ((const float4*)in)[i];
    ushort4 u;
    u.x = f2bf(f.x); u.y = f2bf(f.y); u.z = f2bf(f.z); u.w = f2bf(f.w);
    ((ushort4*)out)[i] = u;
}

// ---------------- W [K][N] f32 -> W^T [N][K] bf16 ----------------
__global__ __launch_bounds__(256) void transpose_w(const float* __restrict__ in,
                                                   u16* __restrict__ out) {
    __shared__ float tS[32][33];
    const int x = threadIdx.x, y = threadIdx.y;      // block (32,8)
    const int bx = blockIdx.x * 32, by = blockIdx.y * 32;
    #pragma unroll
    for (int j = 0; j < 4; j++)
        tS[y + j * 8][x] = in[(long)(by + y + j * 8) * HID_ + bx + x];
    __syncthreads();
    #pragma unroll
    for (int j = 0; j < 4; j++)
        out[(long)(bx + y + j * 8) * HID_ + by + x] = f2bf(tS[x][y + j * 8]);
}

// ---------------- bf16 MFMA GEMM: Y = A(MxK) @ Bt^T, Bt = [N][K] ----------------
// 128x128 tile, 4 waves (2x2 of 64x64), BK=32, single-buffer 2-barrier (m97 structure).
template<int OUTBF>
__global__ __launch_bounds__(256, 3) void gemm_bf16(const u16* __restrict__ A,
                                                    const u16* __restrict__ Bt,
                                                    u16* __restrict__ outb,
                                                    float* __restrict__ outf,
                                                    int K) {
    __shared__ u16 As[128 * 32];
    __shared__ u16 Bs[128 * 32];
    const int t = threadIdx.x;
    const int lane = t & 63;
    const int w = t >> 6;
    const int qlane = lane & 15, grp = lane >> 4;
    const int m0 = blockIdx.y * 128, n0 = blockIdx.x * 128;
    const int wr = w >> 1, wc = w & 1;

    f32x4 acc[4][4];
    #pragma unroll
    for (int i = 0; i < 4; i++)
        #pragma unroll
        for (int j = 0; j < 4; j++) acc[i][j] = (f32x4){0.f, 0.f, 0.f, 0.f};

    const int srow = (lane >> 2);         // 16 rows per 1024B chunk
    const int scol = (lane & 3) * 8;      // 8 ushorts = 16B per lane
    const int nkt = K >> 5;
    for (int kt = 0; kt < nkt; kt++) {
        const int k0 = kt << 5;
        #pragma unroll
        for (int c = 0; c < 2; c++) {
            const int chunk = w * 2 + c;
            const int row = chunk * 16 + srow;
            gll16(A  + (long)(m0 + row) * K + k0 + scol, As + chunk * 512);
            gll16(Bt + (long)(n0 + row) * K + k0 + scol, Bs + chunk * 512);
        }
        __syncthreads();
        bf16x8 af[4], bfr[4];
        #pragma unroll
        for (int i = 0; i < 4; i++) {
            af[i]  = *(const bf16x8*)(As + (wr * 64 + i * 16 + qlane) * 32 + grp * 8);
            bfr[i] = *(const bf16x8*)(Bs + (wc * 64 + i * 16 + qlane) * 32 + grp * 8);
        }
        #pragma unroll
        for (int mf = 0; mf < 4; mf++)
            #pragma unroll
            for (int nf = 0; nf < 4; nf++)
                acc[mf][nf] = __builtin_amdgcn_mfma_f32_16x16x32_bf16(af[mf], bfr[nf], acc[mf][nf], 0, 0, 0);
        __syncthreads();
    }

    #pragma unroll
    for (int mf = 0; mf < 4; mf++)
        #pragma unroll
        for (int nf = 0; nf < 4; nf++) {
            const int gn = n0 + wc * 64 + nf * 16 + qlane;
            #pragma unroll
            for (int r = 0; r < 4; r++) {
                const int m = m0 + wr * 64 + mf * 16 + grp * 4 + r;
                if (OUTBF) {
                    outb[((long)(gn >> 10)) * ((long)4096 * 1024) + (long)m * 1024 + (gn & 1023)]
                        = f2bf(acc[mf][nf][r]);
                } else {
                    outf[(long)m * 1024 + gn] = acc[mf][nf][r];
                }
            }
        }
}

// ---------------- RoPE in place on bf16 q and k ----------------
__global__ __launch_bounds__(256) void rope_bf16(u16* __restrict__ q, u16* __restrict__ k,
                                                 const float* __restrict__ cosb,
                                                 const float* __restrict__ sinb) {
    int tid = blockIdx.x * 256 + threadIdx.x;        // B*S*H*8 threads
    int dg = tid & 7;
    int h  = (tid >> 3) & (H_ - 1);
    int s  = (tid >> 7) & (S_ - 1);
    int b  = tid >> 18;
    const int d0 = dg * 4;
    long base = ((long)(b * S_ + s) * H_ + h) * D_;
    float4 cl = *(const float4*)&cosb[s * D_ + d0];
    float4 ch = *(const float4*)&cosb[s * D_ + d0 + 32];
    float4 sl = *(const float4*)&sinb[s * D_ + d0];
    float4 sh = *(const float4*)&sinb[s * D_ + d0 + 32];
    #pragma unroll
    for (int which = 0; which < 2; which++) {
        u16* p = which ? k : q;
        ushort4 lo = *(const ushort4*)&p[base + d0];
        ushort4 hi = *(const ushort4*)&p[base + d0 + 32];
        float l0 = __bfloat162float(*(__hip_bfloat16*)&lo.x), l1 = __bfloat162float(*(__hip_bfloat16*)&lo.y);
        float l2 = __bfloat162float(*(__hip_bfloat16*)&lo.z), l3 = __bfloat162float(*(__hip_bfloat16*)&lo.w);
        float h0 = __bfloat162float(*(__hip_bfloat16*)&hi.x), h1 = __bfloat162float(*(__hip_bfloat16*)&hi.y);
        float h2 = __bfloat162float(*(__hip_bfloat16*)&hi.z), h3 = __bfloat162float(*(__hip_bfloat16*)&hi.w);
        ushort4 nlo, nhi;
        nlo.x = f2bf(l0 * cl.x - h0 * sl.x); nlo.y = f2bf(l1 * cl.y - h1 * sl.y);
        nlo.z = f2bf(l2 * cl.z - h2 * sl.z); nlo.w = f2bf(l3 * cl.w - h3 * sl.w);
        nhi.x = f2bf(h0 * ch.x + l0 * sh.x); nhi.y = f2bf(h1 * ch.y + l1 * sh.y);
        nhi.z = f2bf(h2 * ch.z + l2 * sh.z); nhi.w = f2bf(h3 * ch.w + l3 * sh.w);
        *(ushort4*)&p[base + d0]      = nlo;
        *(ushort4*)&p[base + d0 + 32] = nhi;
    }
}

// ---------------- MFMA flash attention (bf16 q,k,v,ctx) ----------------
__global__ __launch_bounds__(256) void attn_mfma(const u16* __restrict__ q,
                                                 const u16* __restrict__ k,
                                                 const u16* __restrict__ v,
                                                 const float* __restrict__ rel_bias,
                                                 u16* __restrict__ ctx) {
    __shared__ __align__(16) unsigned char kS[64 * 128];      // K tile [k][d] bf16
    __shared__ __align__(16) unsigned char vT[64 * 128];      // V tile transposed [d][k] bf16
    __shared__ __align__(16) unsigned char pS[4 * 16 * 128];  // per-wave P [q][k] bf16
    __shared__ float bb[128];

    const int t    = threadIdx.x;
    const int lane = t & 63;
    const int w    = t >> 6;
    const int qt = blockIdx.x, h = blockIdx.y, b = blockIdx.z;
    const int q0 = qt * 64;
    const int wq = w * 16;
    const int qlane = lane & 15;
    const int grp   = lane >> 4;

    // Q fragments (B-operand)
    bf16x8 qf[2];
    {
        const u16* qrow = q + ((long)(b * S_ + q0 + wq + qlane) * H_ + h) * D_;
        #pragma unroll
        for (int ds_ = 0; ds_ < 2; ds_++)
            qf[ds_] = *(const bf16x8*)(qrow + ds_ * 32 + grp * 8);
    }

    f32x4 oacc[4];
    #pragma unroll
    for (int db = 0; db < 4; db++) oacc[db] = (f32x4){0.f, 0.f, 0.f, 0.f};
    float m_run = -1.0e30f, l_run = 0.f;

    for (int kt = 0; kt <= qt; kt++) {
        const int k0 = kt * 64;
        #pragma unroll
        for (int i = 0; i < 4; i++) {
            int idx = t + i * 256;
            int r  = idx >> 4;
            int cf = (idx & 15) * 4;
            long g = ((long)(b * S_ + k0 + r) * H_ + h) * D_ + cf;
            ushort4 k4 = *(const ushort4*)&k[g];
            ushort4 v4 = *(const ushort4*)&v[g];
            *(ushort4*)(kS + swz(r, cf * 2)) = k4;
            *(u16*)(vT + swz(cf + 0, r * 2)) = v4.x;
            *(u16*)(vT + swz(cf + 1, r * 2)) = v4.y;
            *(u16*)(vT + swz(cf + 2, r * 2)) = v4.z;
            *(u16*)(vT + swz(cf + 3, r * 2)) = v4.w;
        }
        if (t < 128) {
            int rp = (q0 - k0) + t - 63;
            float bv = 0.f;
            if (rp >= 0) {
                int bucket;
                if (rp < 16) bucket = rp;
                else {
                    int lg = (int)(logf((float)rp * 0.0625f) * 7.69437361f);
                    bucket = 16 + lg;
                    if (bucket > 31) bucket = 31;
                }
                bv = rel_bias[bucket * H_ + h];
            }
            bb[t] = bv;
        }
        __syncthreads();

        // QK^T swapped: sacc[kb][r] = S[k0+kb*16+grp*4+r][q0+wq+qlane]
        f32x4 sacc[4];
        #pragma unroll
        for (int kb = 0; kb < 4; kb++) {
            sacc[kb] = (f32x4){0.f, 0.f, 0.f, 0.f};
            #pragma unroll
            for (int ds_ = 0; ds_ < 2; ds_++) {
                bf16x8 kf = *(const bf16x8*)(kS + swz(kb * 16 + qlane, ds_ * 64 + grp * 16));
                sacc[kb] = __builtin_amdgcn_mfma_f32_16x16x32_bf16(kf, qf[ds_], sacc[kb], 0, 0, 0);
            }
        }

        // bias + mask + online softmax
        float pv_[4][4];
        float tmax = -1.0e30f;
        #pragma unroll
        for (int kb = 0; kb < 4; kb++)
            #pragma unroll
            for (int r = 0; r < 4; r++) {
                int k_l = kb * 16 + grp * 4 + r;
                float s = sacc[kb][r] * 0.125f + bb[wq + qlane - k_l + 63];
                s = ((k0 + k_l) <= (q0 + wq + qlane)) ? s : -1.0e9f;
                pv_[kb][r] = s;
                tmax = fmaxf(tmax, s);
            }
        tmax = fmaxf(tmax, __shfl_xor(tmax, 16));
        tmax = fmaxf(tmax, __shfl_xor(tmax, 32));
        float mnew  = fmaxf(m_run, tmax);
        float scale = __expf(m_run - mnew);
        float tsum = 0.f;
        #pragma unroll
        for (int kb = 0; kb < 4; kb++)
            #pragma unroll
            for (int r = 0; r < 4; r++) {
                float p = __expf(pv_[kb][r] - mnew);
                pv_[kb][r] = p;
                tsum += p;
            }
        tsum += __shfl_xor(tsum, 16);
        tsum += __shfl_xor(tsum, 32);
        l_run = l_run * scale + tsum;
        m_run = mnew;

        // P -> pS (bf16), per-wave region
        #pragma unroll
        for (int kb = 0; kb < 4; kb++) {
            uint2 u;
            u.x = (unsigned)f2bf(pv_[kb][0]) | ((unsigned)f2bf(pv_[kb][1]) << 16);
            u.y = (unsigned)f2bf(pv_[kb][2]) | ((unsigned)f2bf(pv_[kb][3]) << 16);
            *(uint2*)(pS + w * 2048 + swz(qlane, kb * 32 + grp * 8)) = u;
        }

        // rescale O
        float scl[4];
        #pragma unroll
        for (int r = 0; r < 4; r++) scl[r] = __shfl(scale, grp * 4 + r, 64);
        #pragma unroll
        for (int db = 0; db < 4; db++)
            #pragma unroll
            for (int r = 0; r < 4; r++) oacc[db][r] *= scl[r];

        __builtin_amdgcn_wave_barrier();

        // PV
        bf16x8 pf[2];
        #pragma unroll
        for (int ks = 0; ks < 2; ks++)
            pf[ks] = *(const bf16x8*)(pS + w * 2048 + swz(qlane, ks * 64 + grp * 16));
        #pragma unroll
        for (int db = 0; db < 4; db++)
            #pragma unroll
            for (int ks = 0; ks < 2; ks++) {
                bf16x8 vf = *(const bf16x8*)(vT + swz(db * 16 + qlane, ks * 64 + grp * 16));
                oacc[db] = __builtin_amdgcn_mfma_f32_16x16x32_bf16(pf[ks], vf, oacc[db], 0, 0, 0);
            }
        __syncthreads();
    }

    float inv = 1.0f / l_run;
    float invr[4];
    #pragma unroll
    for (int r = 0; r < 4; r++) invr[r] = __shfl(inv, grp * 4 + r, 64);
    #pragma unroll
    for (int r = 0; r < 4; r++) {
        long qg = q0 + wq + grp * 4 + r;
        u16* dst = ctx + (long)(b * S_ + qg) * HID_ + h * D_ + qlane;
        #pragma unroll
        for (int db = 0; db < 4; db++)
            dst[db * 16] = f2bf(oacc[db][r] * invr[r]);
    }
}

extern "C" void kernel_launch(void* const* d_in, const int* in_sizes, int n_in,
                              void* d_out, int out_size, void* d_ws, size_t ws_size,
                              hipStream_t stream) {
    const float* x    = (const float*)d_in[0];
    const float* Wq   = (const float*)d_in[1];
    const float* Wk   = (const float*)d_in[2];
    const float* Wv   = (const float*)d_in[3];
    const float* Wo   = (const float*)d_in[4];
    const float* rb   = (const float*)d_in[5];
    const float* cosb = (const float*)d_in[6];
    const float* sinb = (const float*)d_in[7];
    float* out = (float*)d_out;

    char* wsb = (char*)d_ws;
    u16* xb    = (u16*)(wsb);                        // 8 MB
    u16* wqkvT = (u16*)(wsb + (8L  << 20));          // 6 MB
    u16* woT   = (u16*)(wsb + (14L << 20));          // 2 MB
    u16* qb    = (u16*)(wsb + (16L << 20));          // 8 MB
    u16* kb    = (u16*)(wsb + (24L << 20));          // 8 MB
    u16* vb    = (u16*)(wsb + (32L << 20));          // 8 MB
    u16* ctxb  = (u16*)(wsb + (40L << 20));          // 8 MB

    hipLaunchKernelGGL(convert_x, dim3((B_ * S_ * HID_ / 4) / 256), dim3(256), 0, stream, x, xb);
    dim3 tgrid(32, 32), tblk(32, 8);
    hipLaunchKernelGGL(transpose_w, tgrid, tblk, 0, stream, Wq, wqkvT);
    hipLaunchKernelGGL(transpose_w, tgrid, tblk, 0, stream, Wk, wqkvT + (1L << 20));
    hipLaunchKernelGGL(transpose_w, tgrid, tblk, 0, stream, Wv, wqkvT + (2L << 20));
    hipLaunchKernelGGL(transpose_w, tgrid, tblk, 0, stream, Wo, woT);

    hipLaunchKernelGGL((gemm_bf16<1>), dim3(24, 32), dim3(256), 0, stream,
                       xb, wqkvT, qb, (float*)nullptr, HID_);
    hipLaunchKernelGGL(rope_bf16, dim3((B_ * S_ * H_ * 8) / 256), dim3(256), 0, stream,
                       qb, kb, cosb, sinb);
    hipLaunchKernelGGL(attn_mfma, dim3(S_ / 64, H_, B_), dim3(256), 0, stream,
                       qb, kb, vb, rb, ctxb);
    hipLaunchKernelGGL((gemm_bf16<0>), dim3(8, 32), dim3(256), 0, stream,
                       ctxb, woT, (u16*)nullptr, out, HID_);
}

// Round 4
// 158.245 us; speedup vs baseline: 30.4299x; 1.4665x over previous
//
#include <hip/hip_runtime.h>
#include <hip/hip_bf16.h>
#include <math.h>

#define B_   2
#define S_   2048
#define HID_ 1024
#define H_   16
#define D_   64

typedef __attribute__((ext_vector_type(8))) short bf16x8;
typedef __attribute__((ext_vector_type(4))) short bf16x4;
typedef __attribute__((ext_vector_type(4))) float f32x4;
typedef unsigned short u16;

static __device__ __forceinline__ u16 f2bf(float f) {
    unsigned u = __builtin_bit_cast(unsigned, f);
    u += 0x7fffu + ((u >> 16) & 1u);          // RNE
    return (u16)(u >> 16);
}
static __device__ __forceinline__ int swzK(int row, int colbytes) {
    return row * 128 + (colbytes ^ ((row & 7) << 4));
}
static __device__ __forceinline__ int swzV(int row, int colbytes) {
    return row * 128 + (colbytes ^ ((row & 7) << 4) ^ (((row >> 3) & 1) << 3));
}
static __device__ __forceinline__ void gll16(const void* g, void* l) {
    __builtin_amdgcn_global_load_lds(
        (const __attribute__((address_space(1))) unsigned int*)g,
        (__attribute__((address_space(3))) unsigned int*)l, 16, 0, 0);
}

// ---------------- x (f32) -> bf16 ----------------
__global__ __launch_bounds__(256) void convert_x(const float* __restrict__ in,
                                                 u16* __restrict__ out) {
    int i = blockIdx.x * 256 + threadIdx.x;
    float4 f = ((const float4*)in)[i];
    ushort4 u;
    u.x = f2bf(f.x); u.y = f2bf(f.y); u.z = f2bf(f.z); u.w = f2bf(f.w);
    ((ushort4*)out)[i] = u;
}

// ---------------- W [K][N] f32 -> W^T [N][K] bf16 ----------------
__global__ __launch_bounds__(256) void transpose_w(const float* __restrict__ in,
                                                   u16* __restrict__ out) {
    __shared__ float tS[32][33];
    const int x = threadIdx.x, y = threadIdx.y;
    const int bx = blockIdx.x * 32, by = blockIdx.y * 32;
    #pragma unroll
    for (int j = 0; j < 4; j++)
        tS[y + j * 8][x] = in[(long)(by + y + j * 8) * HID_ + bx + x];
    __syncthreads();
    #pragma unroll
    for (int j = 0; j < 4; j++)
        out[(long)(bx + y + j * 8) * HID_ + by + x] = f2bf(tS[x][y + j * 8]);
}

// ---------------- bf16 MFMA GEMM: Y = A(MxK) @ Bt^T, Bt = [N][K] ----------------
template<int OUTBF>
__global__ __launch_bounds__(256, 3) void gemm_bf16(const u16* __restrict__ A,
                                                    const u16* __restrict__ Bt,
                                                    u16* __restrict__ outb,
                                                    float* __restrict__ outf,
                                                    int K) {
    __shared__ u16 As[128 * 32];
    __shared__ u16 Bs[128 * 32];
    const int t = threadIdx.x;
    const int lane = t & 63;
    const int w = t >> 6;
    const int qlane = lane & 15, grp = lane >> 4;
    const int m0 = blockIdx.y * 128, n0 = blockIdx.x * 128;
    const int wr = w >> 1, wc = w & 1;

    f32x4 acc[4][4];
    #pragma unroll
    for (int i = 0; i < 4; i++)
        #pragma unroll
        for (int j = 0; j < 4; j++) acc[i][j] = (f32x4){0.f, 0.f, 0.f, 0.f};

    const int srow = (lane >> 2);
    const int scol = (lane & 3) * 8;
    const int nkt = K >> 5;
    for (int kt = 0; kt < nkt; kt++) {
        const int k0 = kt << 5;
        #pragma unroll
        for (int c = 0; c < 2; c++) {
            const int chunk = w * 2 + c;
            const int row = chunk * 16 + srow;
            gll16(A  + (long)(m0 + row) * K + k0 + scol, As + chunk * 512);
            gll16(Bt + (long)(n0 + row) * K + k0 + scol, Bs + chunk * 512);
        }
        __syncthreads();
        bf16x8 af[4], bfr[4];
        #pragma unroll
        for (int i = 0; i < 4; i++) {
            af[i]  = *(const bf16x8*)(As + (wr * 64 + i * 16 + qlane) * 32 + grp * 8);
            bfr[i] = *(const bf16x8*)(Bs + (wc * 64 + i * 16 + qlane) * 32 + grp * 8);
        }
        #pragma unroll
        for (int mf = 0; mf < 4; mf++)
            #pragma unroll
            for (int nf = 0; nf < 4; nf++)
                acc[mf][nf] = __builtin_amdgcn_mfma_f32_16x16x32_bf16(af[mf], bfr[nf], acc[mf][nf], 0, 0, 0);
        __syncthreads();
    }

    #pragma unroll
    for (int mf = 0; mf < 4; mf++)
        #pragma unroll
        for (int nf = 0; nf < 4; nf++) {
            const int gn = n0 + wc * 64 + nf * 16 + qlane;
            #pragma unroll
            for (int r = 0; r < 4; r++) {
                const int m = m0 + wr * 64 + mf * 16 + grp * 4 + r;
                if (OUTBF) {
                    outb[((long)(gn >> 10)) * ((long)4096 * 1024) + (long)m * 1024 + (gn & 1023)]
                        = f2bf(acc[mf][nf][r]);
                } else {
                    outf[(long)m * 1024 + gn] = acc[mf][nf][r];
                }
            }
        }
}

// ---------------- RoPE in place on bf16 q and k ----------------
__global__ __launch_bounds__(256) void rope_bf16(u16* __restrict__ q, u16* __restrict__ k,
                                                 const float* __restrict__ cosb,
                                                 const float* __restrict__ sinb) {
    int tid = blockIdx.x * 256 + threadIdx.x;
    int dg = tid & 7;
    int h  = (tid >> 3) & (H_ - 1);
    int s  = (tid >> 7) & (S_ - 1);
    int b  = tid >> 18;
    const int d0 = dg * 4;
    long base = ((long)(b * S_ + s) * H_ + h) * D_;
    float4 cl = *(const float4*)&cosb[s * D_ + d0];
    float4 ch = *(const float4*)&cosb[s * D_ + d0 + 32];
    float4 sl = *(const float4*)&sinb[s * D_ + d0];
    float4 sh = *(const float4*)&sinb[s * D_ + d0 + 32];
    #pragma unroll
    for (int which = 0; which < 2; which++) {
        u16* p = which ? k : q;
        ushort4 lo = *(const ushort4*)&p[base + d0];
        ushort4 hi = *(const ushort4*)&p[base + d0 + 32];
        float l0 = __bfloat162float(*(__hip_bfloat16*)&lo.x), l1 = __bfloat162float(*(__hip_bfloat16*)&lo.y);
        float l2 = __bfloat162float(*(__hip_bfloat16*)&lo.z), l3 = __bfloat162float(*(__hip_bfloat16*)&lo.w);
        float h0 = __bfloat162float(*(__hip_bfloat16*)&hi.x), h1 = __bfloat162float(*(__hip_bfloat16*)&hi.y);
        float h2 = __bfloat162float(*(__hip_bfloat16*)&hi.z), h3 = __bfloat162float(*(__hip_bfloat16*)&hi.w);
        ushort4 nlo, nhi;
        nlo.x = f2bf(l0 * cl.x - h0 * sl.x); nlo.y = f2bf(l1 * cl.y - h1 * sl.y);
        nlo.z = f2bf(l2 * cl.z - h2 * sl.z); nlo.w = f2bf(l3 * cl.w - h3 * sl.w);
        nhi.x = f2bf(h0 * ch.x + l0 * sh.x); nhi.y = f2bf(h1 * ch.y + l1 * sh.y);
        nhi.z = f2bf(h2 * ch.z + l2 * sh.z); nhi.w = f2bf(h3 * ch.w + l3 * sh.w);
        *(ushort4*)&p[base + d0]      = nlo;
        *(ushort4*)&p[base + d0 + 32] = nhi;
    }
}

// ---------------- MFMA flash attention, double-buffered, P-in-registers ----------------
#define VCOMP(vv, j) ((j) == 0 ? (vv).x : (j) == 1 ? (vv).y : (j) == 2 ? (vv).z : (vv).w)

__global__ __launch_bounds__(256) void attn_mfma(const u16* __restrict__ q,
                                                 const u16* __restrict__ k,
                                                 const u16* __restrict__ v,
                                                 const float* __restrict__ rel_bias,
                                                 u16* __restrict__ ctx) {
    __shared__ __align__(16) unsigned char kS[2][8192];   // K [k][d] bf16, swzK
    __shared__ __align__(16) unsigned char vS[2][8192];   // V^T [d][k] bf16, swzV
    __shared__ float bb[2][128];

    const int t    = threadIdx.x;
    const int lane = t & 63;
    const int w    = t >> 6;
    // XCD-aware decode: blocks sharing (b,h) land on the same XCD (n % 8 const).
    const int n    = blockIdx.x;
    const int hb   = (n & 7) + ((n >> 8) << 3);   // hblo + 8*hbhi
    const int qt   = (n >> 3) & 31;
    const int h    = hb & 15, b = hb >> 4;
    const int q0   = qt * 64;
    const int wq   = w * 16;
    const int qlane = lane & 15;
    const int grp   = lane >> 4;

    const int R  = (t >> 4) * 4;     // staging rows R..R+3
    const int cf = (t & 15) * 4;     // staging cols cf..cf+3

    // Q fragments (B-operand of swapped QK^T)
    bf16x8 qf0, qf1;
    {
        const u16* qrow = q + ((long)(b * S_ + q0 + wq + qlane) * H_ + h) * D_;
        qf0 = *(const bf16x8*)(qrow + grp * 8);
        qf1 = *(const bf16x8*)(qrow + 32 + grp * 8);
    }

    f32x4 oacc[4];
    #pragma unroll
    for (int db = 0; db < 4; db++) oacc[db] = (f32x4){0.f, 0.f, 0.f, 0.f};
    float m_run = -1.0e30f, l_run = 0.f;

    ushort4 kreg[4], vreg[4];
    float breg = 0.f;

    auto prefetch = [&](int k0) {
        #pragma unroll
        for (int i = 0; i < 4; i++) {
            long g = ((long)(b * S_ + k0 + R + i) * H_ + h) * D_ + cf;
            kreg[i] = *(const ushort4*)&k[g];
            vreg[i] = *(const ushort4*)&v[g];
        }
        if (t < 128) {
            int rp = (q0 - k0) + t - 63;
            float bv = 0.f;
            if (rp >= 0) {
                int bucket;
                if (rp < 16) bucket = rp;
                else {
                    int lg = (int)(logf((float)rp * 0.0625f) * 7.69437361f);
                    bucket = 16 + lg;
                    if (bucket > 31) bucket = 31;
                }
                bv = rel_bias[bucket * H_ + h];
            }
            breg = bv;
        }
    };
    auto writetile = [&](int buf) {
        #pragma unroll
        for (int i = 0; i < 4; i++)
            *(ushort4*)(kS[buf] + swzK(R + i, cf * 2)) = kreg[i];
        #pragma unroll
        for (int j = 0; j < 4; j++) {   // register 4x4 transpose of V block
            ushort4 tc;
            tc.x = VCOMP(vreg[0], j); tc.y = VCOMP(vreg[1], j);
            tc.z = VCOMP(vreg[2], j); tc.w = VCOMP(vreg[3], j);
            *(ushort4*)(vS[buf] + swzV(cf + j, R * 2)) = tc;
        }
        if (t < 128) bb[buf][t] = breg;
    };

    prefetch(0);
    writetile(0);
    __syncthreads();

    int cur = 0;
    for (int kt = 0; kt <= qt; kt++) {
        const int k0 = kt * 64;
        if (kt < qt) prefetch(k0 + 64);

        // ---- QK^T swapped: sacc[kb][r] = S[k0+kb*16+grp*4+r][q0+wq+qlane] ----
        __builtin_amdgcn_s_setprio(1);
        f32x4 sacc[4];
        #pragma unroll
        for (int kb = 0; kb < 4; kb++) {
            sacc[kb] = (f32x4){0.f, 0.f, 0.f, 0.f};
            bf16x8 kf0 = *(const bf16x8*)(kS[cur] + swzK(kb * 16 + qlane, grp * 16));
            bf16x8 kf1 = *(const bf16x8*)(kS[cur] + swzK(kb * 16 + qlane, 64 + grp * 16));
            sacc[kb] = __builtin_amdgcn_mfma_f32_16x16x32_bf16(kf0, qf0, sacc[kb], 0, 0, 0);
            sacc[kb] = __builtin_amdgcn_mfma_f32_16x16x32_bf16(kf1, qf1, sacc[kb], 0, 0, 0);
        }
        __builtin_amdgcn_s_setprio(0);

        // ---- bias + mask + online softmax ----
        float pv_[4][4];
        float tmax = -1.0e30f;
        #pragma unroll
        for (int kb = 0; kb < 4; kb++)
            #pragma unroll
            for (int r = 0; r < 4; r++) {
                int k_l = kb * 16 + grp * 4 + r;
                float s = sacc[kb][r] * 0.125f + bb[cur][wq + qlane - k_l + 63];
                s = ((k0 + k_l) <= (q0 + wq + qlane)) ? s : -1.0e9f;
                pv_[kb][r] = s;
                tmax = fmaxf(tmax, s);
            }
        tmax = fmaxf(tmax, __shfl_xor(tmax, 16));
        tmax = fmaxf(tmax, __shfl_xor(tmax, 32));
        float mnew  = fmaxf(m_run, tmax);
        float scale = __expf(m_run - mnew);
        float tsum = 0.f;
        #pragma unroll
        for (int kb = 0; kb < 4; kb++)
            #pragma unroll
            for (int r = 0; r < 4; r++) {
                float p = __expf(pv_[kb][r] - mnew);
                pv_[kb][r] = p;
                tsum += p;
            }
        tsum += __shfl_xor(tsum, 16);
        tsum += __shfl_xor(tsum, 32);
        l_run = l_run * scale + tsum;
        m_run = mnew;

        // ---- pack P fragments in permuted k-order: elem j<4 -> kb=2ks, j>=4 -> kb=2ks+1 ----
        bf16x8 pf[2];
        #pragma unroll
        for (int ks = 0; ks < 2; ks++) {
            bf16x8 f;
            f[0] = (short)f2bf(pv_[2 * ks][0]);     f[1] = (short)f2bf(pv_[2 * ks][1]);
            f[2] = (short)f2bf(pv_[2 * ks][2]);     f[3] = (short)f2bf(pv_[2 * ks][3]);
            f[4] = (short)f2bf(pv_[2 * ks + 1][0]); f[5] = (short)f2bf(pv_[2 * ks + 1][1]);
            f[6] = (short)f2bf(pv_[2 * ks + 1][2]); f[7] = (short)f2bf(pv_[2 * ks + 1][3]);
            pf[ks] = f;
        }

        // ---- rescale O ----
        float scl[4];
        #pragma unroll
        for (int r = 0; r < 4; r++) scl[r] = __shfl(scale, grp * 4 + r, 64);
        #pragma unroll
        for (int db = 0; db < 4; db++)
            #pragma unroll
            for (int r = 0; r < 4; r++) oacc[db][r] *= scl[r];

        // ---- PV: V^T b64-pairs at the same permuted k positions ----
        __builtin_amdgcn_s_setprio(1);
        #pragma unroll
        for (int db = 0; db < 4; db++) {
            #pragma unroll
            for (int ks = 0; ks < 2; ks++) {
                bf16x4 lo = *(const bf16x4*)(vS[cur] + swzV(db * 16 + qlane, ks * 64 + grp * 8));
                bf16x4 hi = *(const bf16x4*)(vS[cur] + swzV(db * 16 + qlane, ks * 64 + 32 + grp * 8));
                bf16x8 vf = __builtin_shufflevector(lo, hi, 0, 1, 2, 3, 4, 5, 6, 7);
                oacc[db] = __builtin_amdgcn_mfma_f32_16x16x32_bf16(pf[ks], vf, oacc[db], 0, 0, 0);
            }
        }
        __builtin_amdgcn_s_setprio(0);

        if (kt < qt) writetile(cur ^ 1);
        __syncthreads();
        cur ^= 1;
    }

    float inv = 1.0f / l_run;
    float invr[4];
    #pragma unroll
    for (int r = 0; r < 4; r++) invr[r] = __shfl(inv, grp * 4 + r, 64);
    #pragma unroll
    for (int r = 0; r < 4; r++) {
        long qg = q0 + wq + grp * 4 + r;
        u16* dst = ctx + (long)(b * S_ + qg) * HID_ + h * D_ + qlane;
        #pragma unroll
        for (int db = 0; db < 4; db++)
            dst[db * 16] = f2bf(oacc[db][r] * invr[r]);
    }
}

extern "C" void kernel_launch(void* const* d_in, const int* in_sizes, int n_in,
                              void* d_out, int out_size, void* d_ws, size_t ws_size,
                              hipStream_t stream) {
    const float* x    = (const float*)d_in[0];
    const float* Wq   = (const float*)d_in[1];
    const float* Wk   = (const float*)d_in[2];
    const float* Wv   = (const float*)d_in[3];
    const float* Wo   = (const float*)d_in[4];
    const float* rb   = (const float*)d_in[5];
    const float* cosb = (const float*)d_in[6];
    const float* sinb = (const float*)d_in[7];
    float* out = (float*)d_out;

    char* wsb = (char*)d_ws;
    u16* xb    = (u16*)(wsb);
    u16* wqkvT = (u16*)(wsb + (8L  << 20));
    u16* woT   = (u16*)(wsb + (14L << 20));
    u16* qb    = (u16*)(wsb + (16L << 20));
    u16* kb    = (u16*)(wsb + (24L << 20));
    u16* vb    = (u16*)(wsb + (32L << 20));
    u16* ctxb  = (u16*)(wsb + (40L << 20));

    hipLaunchKernelGGL(convert_x, dim3((B_ * S_ * HID_ / 4) / 256), dim3(256), 0, stream, x, xb);
    dim3 tgrid(32, 32), tblk(32, 8);
    hipLaunchKernelGGL(transpose_w, tgrid, tblk, 0, stream, Wq, wqkvT);
    hipLaunchKernelGGL(transpose_w, tgrid, tblk, 0, stream, Wk, wqkvT + (1L << 20));
    hipLaunchKernelGGL(transpose_w, tgrid, tblk, 0, stream, Wv, wqkvT + (2L << 20));
    hipLaunchKernelGGL(transpose_w, tgrid, tblk, 0, stream, Wo, woT);

    hipLaunchKernelGGL((gemm_bf16<1>), dim3(24, 32), dim3(256), 0, stream,
                       xb, wqkvT, qb, (float*)nullptr, HID_);
    hipLaunchKernelGGL(rope_bf16, dim3((B_ * S_ * H_ * 8) / 256), dim3(256), 0, stream,
                       qb, kb, cosb, sinb);
    hipLaunchKernelGGL(attn_mfma, dim3(S_ / 64 * H_ * B_), dim3(256), 0, stream,
                       qb, kb, vb, rb, ctxb);
    hipLaunchKernelGGL((gemm_bf16<0>), dim3(8, 32), dim3(256), 0, stream,
                       ctxb, woT, (u16*)nullptr, out, HID_);
}

// Round 5
// 131.819 us; speedup vs baseline: 36.5302x; 1.2005x over previous
//
#include <hip/hip_runtime.h>
#include <hip/hip_bf16.h>
#include <math.h>

#define B_   2
#define S_   2048
#define HID_ 1024
#define H_   16
#define D_   64

typedef __attribute__((ext_vector_type(8))) short bf16x8;
typedef __attribute__((ext_vector_type(4))) short bf16x4;
typedef __attribute__((ext_vector_type(4))) float f32x4;
typedef __attribute__((ext_vector_type(4))) unsigned uint4v;
typedef unsigned short u16;

template<int V> struct IC { static constexpr int val = V; };

static __device__ __forceinline__ u16 f2bf(float f) {
    unsigned u = __builtin_bit_cast(unsigned, f);
    u += 0x7fffu + ((u >> 16) & 1u);          // RNE
    return (u16)(u >> 16);
}
static __device__ __forceinline__ unsigned cvtpk(float lo, float hi) {
    unsigned r;
    asm("v_cvt_pk_bf16_f32 %0, %1, %2" : "=v"(r) : "v"(lo), "v"(hi));
    return r;
}
static __device__ __forceinline__ int swzK(int row, int colbytes) {
    return row * 128 + (colbytes ^ ((row & 7) << 4));
}
static __device__ __forceinline__ int swzV(int row, int colbytes) {
    return row * 128 + (colbytes ^ ((row & 7) << 4) ^ (((row >> 3) & 1) << 3));
}
static __device__ __forceinline__ void gll16(const void* g, void* l) {
    __builtin_amdgcn_global_load_lds(
        (const __attribute__((address_space(1))) unsigned int*)g,
        (__attribute__((address_space(3))) unsigned int*)l, 16, 0, 0);
}

// ---------------- x (f32) -> bf16 ----------------
__global__ __launch_bounds__(256) void convert_x(const float* __restrict__ in,
                                                 u16* __restrict__ out) {
    int i = blockIdx.x * 256 + threadIdx.x;
    float4 f = ((const float4*)in)[i];
    ushort4 u;
    u.x = f2bf(f.x); u.y = f2bf(f.y); u.z = f2bf(f.z); u.w = f2bf(f.w);
    ((ushort4*)out)[i] = u;
}

// ---------------- 4x W [K][N] f32 -> W^T [N][K] bf16, one launch ----------------
__global__ __launch_bounds__(256) void transpose_w4(const float* __restrict__ W0,
                                                    const float* __restrict__ W1,
                                                    const float* __restrict__ W2,
                                                    const float* __restrict__ W3,
                                                    u16* __restrict__ o0,
                                                    u16* __restrict__ o1,
                                                    u16* __restrict__ o2,
                                                    u16* __restrict__ o3) {
    __shared__ float tS[32][33];
    const int z = blockIdx.z;
    const float* in = z == 0 ? W0 : z == 1 ? W1 : z == 2 ? W2 : W3;
    u16* out       = z == 0 ? o0 : z == 1 ? o1 : z == 2 ? o2 : o3;
    const int x = threadIdx.x, y = threadIdx.y;
    const int bx = blockIdx.x * 32, by = blockIdx.y * 32;
    #pragma unroll
    for (int j = 0; j < 4; j++)
        tS[y + j * 8][x] = in[(long)(by + y + j * 8) * HID_ + bx + x];
    __syncthreads();
    #pragma unroll
    for (int j = 0; j < 4; j++)
        out[(long)(bx + y + j * 8) * HID_ + by + x] = f2bf(tS[x][y + j * 8]);
}

// ---------------- bf16 MFMA GEMM: Y = A(MxK) @ Bt^T, Bt = [N][K] ----------------
// OUTBF: bf16 out split q/k/v by gn>>10. ROPE: apply rotary to q,k halves in
// epilogue (d and d+32 are nf and nf+2 -> thread-local), and fold 0.125 into q.
template<int OUTBF, int ROPE>
__global__ __launch_bounds__(256, 3) void gemm_bf16(const u16* __restrict__ A,
                                                    const u16* __restrict__ Bt,
                                                    u16* __restrict__ outb,
                                                    float* __restrict__ outf,
                                                    const float* __restrict__ cosb,
                                                    const float* __restrict__ sinb,
                                                    int K) {
    __shared__ u16 As[128 * 32];
    __shared__ u16 Bs[128 * 32];
    const int t = threadIdx.x;
    const int lane = t & 63;
    const int w = t >> 6;
    const int qlane = lane & 15, grp = lane >> 4;
    const int m0 = blockIdx.y * 128, n0 = blockIdx.x * 128;
    const int wr = w >> 1, wc = w & 1;

    f32x4 acc[4][4];
    #pragma unroll
    for (int i = 0; i < 4; i++)
        #pragma unroll
        for (int j = 0; j < 4; j++) acc[i][j] = (f32x4){0.f, 0.f, 0.f, 0.f};

    const int srow = (lane >> 2);
    const int scol = (lane & 3) * 8;
    const int nkt = K >> 5;
    for (int kt = 0; kt < nkt; kt++) {
        const int k0 = kt << 5;
        #pragma unroll
        for (int c = 0; c < 2; c++) {
            const int chunk = w * 2 + c;
            const int row = chunk * 16 + srow;
            gll16(A  + (long)(m0 + row) * K + k0 + scol, As + chunk * 512);
            gll16(Bt + (long)(n0 + row) * K + k0 + scol, Bs + chunk * 512);
        }
        __syncthreads();
        bf16x8 af[4], bfr[4];
        #pragma unroll
        for (int i = 0; i < 4; i++) {
            af[i]  = *(const bf16x8*)(As + (wr * 64 + i * 16 + qlane) * 32 + grp * 8);
            bfr[i] = *(const bf16x8*)(Bs + (wc * 64 + i * 16 + qlane) * 32 + grp * 8);
        }
        #pragma unroll
        for (int mf = 0; mf < 4; mf++)
            #pragma unroll
            for (int nf = 0; nf < 4; nf++)
                acc[mf][nf] = __builtin_amdgcn_mfma_f32_16x16x32_bf16(af[mf], bfr[nf], acc[mf][nf], 0, 0, 0);
        __syncthreads();
    }

    const int gnb = n0 + wc * 64;     // head-aligned 64-col half
    #pragma unroll
    for (int mf = 0; mf < 4; mf++) {
        #pragma unroll
        for (int r = 0; r < 4; r++) {
            const int m = m0 + wr * 64 + mf * 16 + grp * 4 + r;
            float a0 = acc[mf][0][r], a1 = acc[mf][1][r];
            float a2 = acc[mf][2][r], a3 = acc[mf][3][r];
            if (ROPE && gnb < 2048) {             // q or k head
                const int s = m & (S_ - 1);
                const float* cr = cosb + s * 64;
                const float* sr = sinb + s * 64;
                float c0 = cr[qlane], c1 = cr[qlane + 16], c2 = cr[qlane + 32], c3 = cr[qlane + 48];
                float z0 = sr[qlane], z1 = sr[qlane + 16], z2 = sr[qlane + 32], z3 = sr[qlane + 48];
                float n0v = a0 * c0 - a2 * z0;
                float n1v = a1 * c1 - a3 * z1;
                float n2v = a2 * c2 + a0 * z2;
                float n3v = a3 * c3 + a1 * z3;
                if (gnb < 1024) {                  // q: fold attention scale
                    n0v *= 0.125f; n1v *= 0.125f; n2v *= 0.125f; n3v *= 0.125f;
                }
                a0 = n0v; a1 = n1v; a2 = n2v; a3 = n3v;
            }
            if (OUTBF) {
                const float av[4] = {a0, a1, a2, a3};
                #pragma unroll
                for (int nf = 0; nf < 4; nf++) {
                    const int gn = gnb + nf * 16 + qlane;
                    outb[((long)(gn >> 10)) * ((long)4096 * 1024) + (long)m * 1024 + (gn & 1023)]
                        = f2bf(av[nf]);
                }
            } else {
                const float av[4] = {a0, a1, a2, a3};
                #pragma unroll
                for (int nf = 0; nf < 4; nf++)
                    outf[(long)m * 1024 + gnb + nf * 16 + qlane] = av[nf];
            }
        }
    }
}

// ---------------- MFMA flash attention ----------------
// Zigzag qt across rounds for CU load balance; far tiles (qt-kt>=3) use
// constant bias (bucket==31 for rp>=113) + no mask; diag masked; defer-max.
#define VCOMP(vv, j) ((j) == 0 ? (vv).x : (j) == 1 ? (vv).y : (j) == 2 ? (vv).z : (vv).w)

__global__ __launch_bounds__(256) void attn_mfma(const u16* __restrict__ q,
                                                 const u16* __restrict__ k,
                                                 const u16* __restrict__ v,
                                                 const float* __restrict__ rel_bias,
                                                 u16* __restrict__ ctx) {
    __shared__ __align__(16) unsigned char kS[2][8192];   // K [k][d] bf16, swzK
    __shared__ __align__(16) unsigned char vS[2][8192];   // V^T [d][k] bf16, swzV
    __shared__ float bb[2][128];

    const int t    = threadIdx.x;
    const int lane = t & 63;
    const int w    = t >> 6;
    const int n    = blockIdx.x;
    const int rnd  = n >> 8;                     // 0..3
    int qtv        = (n >> 3) & 31;
    if (rnd & 1) qtv = 31 - qtv;                 // zigzag: CU gets 66 tiles always
    const int qt   = qtv;
    const int hb   = (n & 7) + (rnd << 3);       // same (b,h) stays on one XCD
    const int h    = hb & 15, b = hb >> 4;
    const int q0   = qt * 64;
    const int wq   = w * 16;
    const int qlane = lane & 15;
    const int grp   = lane >> 4;

    const int R  = (t >> 4) * 4;     // staging rows R..R+3
    const int cf = (t & 15) * 4;     // staging cols cf..cf+3

    const long bhbase = ((long)b * S_ * H_ + h) * D_;
    const float bfar  = rel_bias[31 * H_ + h];   // bucket 31: all rp >= 113

    bf16x8 qf0, qf1;
    {
        const u16* qrow = q + bhbase + (long)(q0 + wq + qlane) * (H_ * D_);
        qf0 = *(const bf16x8*)(qrow + grp * 8);
        qf1 = *(const bf16x8*)(qrow + 32 + grp * 8);
    }

    f32x4 oacc[4];
    #pragma unroll
    for (int db = 0; db < 4; db++) oacc[db] = (f32x4){0.f, 0.f, 0.f, 0.f};
    float m_run = -1.0e30f, l_run = 0.f;

    ushort4 kreg[4], vreg[4];
    float breg = 0.f;

    auto prefetch = [&](int k0, bool needb) {
        const u16* kp = k + bhbase + (long)(k0 + R) * (H_ * D_) + cf;
        const u16* vp = v + bhbase + (long)(k0 + R) * (H_ * D_) + cf;
        #pragma unroll
        for (int i = 0; i < 4; i++) {
            kreg[i] = *(const ushort4*)(kp + i * (H_ * D_));
            vreg[i] = *(const ushort4*)(vp + i * (H_ * D_));
        }
        if (needb && t < 128) {
            int rp = (q0 - k0) + t - 63;
            float bv = 0.f;
            if (rp >= 0) {
                int bucket;
                if (rp < 16) bucket = rp;
                else {
                    int lg = (int)(logf((float)rp * 0.0625f) * 7.69437361f);
                    bucket = 16 + lg;
                    if (bucket > 31) bucket = 31;
                }
                bv = rel_bias[bucket * H_ + h];
            }
            breg = bv;
        }
    };
    auto writetile = [&](int buf, bool needb) {
        #pragma unroll
        for (int i = 0; i < 4; i++)
            *(ushort4*)(kS[buf] + swzK(R + i, cf * 2)) = kreg[i];
        #pragma unroll
        for (int j = 0; j < 4; j++) {
            ushort4 tc;
            tc.x = VCOMP(vreg[0], j); tc.y = VCOMP(vreg[1], j);
            tc.z = VCOMP(vreg[2], j); tc.w = VCOMP(vreg[3], j);
            *(ushort4*)(vS[buf] + swzV(cf + j, R * 2)) = tc;
        }
        if (needb && t < 128) bb[buf][t] = breg;
    };

    int cur = 0;

    // MODE: 0 = far (const bias, no mask), 1 = near (bias table), 2 = diag (+mask)
    auto tile = [&](int kt, auto mode_tag) {
        constexpr int MODE = decltype(mode_tag)::val;
        const int k0 = kt * 64;
        const bool has_next = kt < qt;
        if (has_next) {
            const int ktn = kt + 1;
            prefetch(k0 + 64, ktn >= qt - 2);
        }

        __builtin_amdgcn_s_setprio(1);
        f32x4 sacc[4];
        #pragma unroll
        for (int kb = 0; kb < 4; kb++) {
            sacc[kb] = (f32x4){0.f, 0.f, 0.f, 0.f};
            bf16x8 kf0 = *(const bf16x8*)(kS[cur] + swzK(kb * 16 + qlane, grp * 16));
            bf16x8 kf1 = *(const bf16x8*)(kS[cur] + swzK(kb * 16 + qlane, 64 + grp * 16));
            sacc[kb] = __builtin_amdgcn_mfma_f32_16x16x32_bf16(kf0, qf0, sacc[kb], 0, 0, 0);
            sacc[kb] = __builtin_amdgcn_mfma_f32_16x16x32_bf16(kf1, qf1, sacc[kb], 0, 0, 0);
        }
        __builtin_amdgcn_s_setprio(0);

        float pv_[4][4];
        float tmax = -1.0e30f;
        #pragma unroll
        for (int kb = 0; kb < 4; kb++) {
            #pragma unroll
            for (int r = 0; r < 4; r++) {
                float s = sacc[kb][r];               // q pre-scaled by 0.125
                if (MODE >= 1) {
                    const int k_l = kb * 16 + grp * 4 + r;
                    s += bb[cur][wq + qlane - k_l + 63];
                    if (MODE == 2)
                        s = ((k0 + k_l) <= (q0 + wq + qlane)) ? s : -1.0e9f;
                }
                pv_[kb][r] = s;
            }
            tmax = fmaxf(tmax,
                   fmaxf(fmaxf(pv_[kb][0], pv_[kb][1]), fmaxf(pv_[kb][2], pv_[kb][3])));
        }
        tmax = fmaxf(tmax, __shfl_xor(tmax, 16));
        tmax = fmaxf(tmax, __shfl_xor(tmax, 32));

        // biased max for far tiles handled via shifted subtractor
        float bofs = (MODE == 0) ? bfar : 0.f;
        float teff = tmax + bofs;
        float msub;
        if (__all(teff <= m_run + 8.0f)) {
            msub = m_run - bofs;                      // defer: keep m, skip rescale
        } else {
            float mnew = fmaxf(m_run, teff);
            float scale = __expf(m_run - mnew);
            l_run *= scale;
            float scl[4];
            #pragma unroll
            for (int r = 0; r < 4; r++) scl[r] = __shfl(scale, grp * 4 + r, 64);
            #pragma unroll
            for (int db = 0; db < 4; db++)
                #pragma unroll
                for (int r = 0; r < 4; r++) oacc[db][r] *= scl[r];
            m_run = mnew;
            msub = mnew - bofs;
        }

        float tsum = 0.f;
        #pragma unroll
        for (int kb = 0; kb < 4; kb++)
            #pragma unroll
            for (int r = 0; r < 4; r++) {
                float p = __expf(pv_[kb][r] - msub);
                pv_[kb][r] = p;
                tsum += p;
            }
        tsum += __shfl_xor(tsum, 16);
        tsum += __shfl_xor(tsum, 32);
        l_run += tsum;

        bf16x8 pf[2];
        #pragma unroll
        for (int ks = 0; ks < 2; ks++) {
            unsigned u0 = cvtpk(pv_[2 * ks][0], pv_[2 * ks][1]);
            unsigned u1 = cvtpk(pv_[2 * ks][2], pv_[2 * ks][3]);
            unsigned u2 = cvtpk(pv_[2 * ks + 1][0], pv_[2 * ks + 1][1]);
            unsigned u3 = cvtpk(pv_[2 * ks + 1][2], pv_[2 * ks + 1][3]);
            pf[ks] = __builtin_bit_cast(bf16x8, (uint4v){u0, u1, u2, u3});
        }

        __builtin_amdgcn_s_setprio(1);
        #pragma unroll
        for (int db = 0; db < 4; db++) {
            #pragma unroll
            for (int ks = 0; ks < 2; ks++) {
                bf16x4 lo = *(const bf16x4*)(vS[cur] + swzV(db * 16 + qlane, ks * 64 + grp * 8));
                bf16x4 hi = *(const bf16x4*)(vS[cur] + swzV(db * 16 + qlane, ks * 64 + 32 + grp * 8));
                bf16x8 vf = __builtin_shufflevector(lo, hi, 0, 1, 2, 3, 4, 5, 6, 7);
                oacc[db] = __builtin_amdgcn_mfma_f32_16x16x32_bf16(pf[ks], vf, oacc[db], 0, 0, 0);
            }
        }
        __builtin_amdgcn_s_setprio(0);

        if (has_next) writetile(cur ^ 1, (kt + 1) >= qt - 2);
        __syncthreads();
        cur ^= 1;
    };

    prefetch(0, 0 >= qt - 2);
    writetile(0, 0 >= qt - 2);
    __syncthreads();

    for (int kt = 0; kt <= qt - 3; kt++) tile(kt, IC<0>{});
    for (int kt = (qt >= 2 ? qt - 2 : 0); kt < qt; kt++) tile(kt, IC<1>{});
    tile(qt, IC<2>{});

    float inv = 1.0f / l_run;
    float invr[4];
    #pragma unroll
    for (int r = 0; r < 4; r++) invr[r] = __shfl(inv, grp * 4 + r, 64);
    #pragma unroll
    for (int r = 0; r < 4; r++) {
        long qg = q0 + wq + grp * 4 + r;
        u16* dst = ctx + (long)(b * S_ + qg) * HID_ + h * D_ + qlane;
        #pragma unroll
        for (int db = 0; db < 4; db++)
            dst[db * 16] = f2bf(oacc[db][r] * invr[r]);
    }
}

extern "C" void kernel_launch(void* const* d_in, const int* in_sizes, int n_in,
                              void* d_out, int out_size, void* d_ws, size_t ws_size,
                              hipStream_t stream) {
    const float* x    = (const float*)d_in[0];
    const float* Wq   = (const float*)d_in[1];
    const float* Wk   = (const float*)d_in[2];
    const float* Wv   = (const float*)d_in[3];
    const float* Wo   = (const float*)d_in[4];
    const float* rb   = (const float*)d_in[5];
    const float* cosb = (const float*)d_in[6];
    const float* sinb = (const float*)d_in[7];
    float* out = (float*)d_out;

    char* wsb = (char*)d_ws;
    u16* xb    = (u16*)(wsb);
    u16* wqkvT = (u16*)(wsb + (8L  << 20));
    u16* woT   = (u16*)(wsb + (14L << 20));
    u16* qb    = (u16*)(wsb + (16L << 20));
    u16* kb    = (u16*)(wsb + (24L << 20));
    u16* vb    = (u16*)(wsb + (32L << 20));
    u16* ctxb  = (u16*)(wsb + (40L << 20));

    hipLaunchKernelGGL(convert_x, dim3((B_ * S_ * HID_ / 4) / 256), dim3(256), 0, stream, x, xb);
    hipLaunchKernelGGL(transpose_w4, dim3(32, 32, 4), dim3(32, 8), 0, stream,
                       Wq, Wk, Wv, Wo,
                       wqkvT, wqkvT + (1L << 20), wqkvT + (2L << 20), woT);

    hipLaunchKernelGGL((gemm_bf16<1, 1>), dim3(24, 32), dim3(256), 0, stream,
                       xb, wqkvT, qb, (float*)nullptr, cosb, sinb, HID_);
    hipLaunchKernelGGL(attn_mfma, dim3(S_ / 64 * H_ * B_), dim3(256), 0, stream,
                       qb, kb, vb, rb, ctxb);
    hipLaunchKernelGGL((gemm_bf16<0, 0>), dim3(8, 32), dim3(256), 0, stream,
                       ctxb, woT, (u16*)nullptr, out, (const float*)nullptr, (const float*)nullptr, HID_);
}

// Round 6
// 121.364 us; speedup vs baseline: 39.6772x; 1.0861x over previous
//
#include <hip/hip_runtime.h>
#include <hip/hip_bf16.h>
#include <math.h>

#define B_   2
#define S_   2048
#define HID_ 1024
#define H_   16
#define D_   64

typedef __attribute__((ext_vector_type(8))) short bf16x8;
typedef __attribute__((ext_vector_type(4))) short bf16x4;
typedef __attribute__((ext_vector_type(4))) float f32x4;
typedef __attribute__((ext_vector_type(4))) unsigned uint4v;
typedef unsigned short u16;

#define LOG2E 1.44269504088896f

static __device__ __forceinline__ u16 f2bf(float f) {
    unsigned u = __builtin_bit_cast(unsigned, f);
    u += 0x7fffu + ((u >> 16) & 1u);          // RNE
    return (u16)(u >> 16);
}
static __device__ __forceinline__ unsigned cvtpk(float lo, float hi) {
    unsigned r;
    asm("v_cvt_pk_bf16_f32 %0, %1, %2" : "=v"(r) : "v"(lo), "v"(hi));
    return r;
}
static __device__ __forceinline__ int swzK(int row, int colbytes) {
    return row * 128 + (colbytes ^ ((row & 7) << 4));
}
static __device__ __forceinline__ int swzV(int row, int colbytes) {
    return row * 128 + (colbytes ^ ((row & 7) << 4) ^ (((row >> 3) & 1) << 3));
}
static __device__ __forceinline__ void gll16(const void* g, void* l) {
    __builtin_amdgcn_global_load_lds(
        (const __attribute__((address_space(1))) unsigned int*)g,
        (__attribute__((address_space(3))) unsigned int*)l, 16, 0, 0);
}

// ---------------- x (f32) -> bf16 ----------------
__global__ __launch_bounds__(256) void convert_x(const float* __restrict__ in,
                                                 u16* __restrict__ out) {
    int i = blockIdx.x * 256 + threadIdx.x;
    float4 f = ((const float4*)in)[i];
    ushort4 u;
    u.x = f2bf(f.x); u.y = f2bf(f.y); u.z = f2bf(f.z); u.w = f2bf(f.w);
    ((ushort4*)out)[i] = u;
}

// ---------------- 4x W [K][N] f32 -> W^T [N][K] bf16, one launch ----------------
__global__ __launch_bounds__(256) void transpose_w4(const float* __restrict__ W0,
                                                    const float* __restrict__ W1,
                                                    const float* __restrict__ W2,
                                                    const float* __restrict__ W3,
                                                    u16* __restrict__ o0,
                                                    u16* __restrict__ o1,
                                                    u16* __restrict__ o2,
                                                    u16* __restrict__ o3) {
    __shared__ float tS[32][33];
    const int z = blockIdx.z;
    const float* in = z == 0 ? W0 : z == 1 ? W1 : z == 2 ? W2 : W3;
    u16* out       = z == 0 ? o0 : z == 1 ? o1 : z == 2 ? o2 : o3;
    const int x = threadIdx.x, y = threadIdx.y;
    const int bx = blockIdx.x * 32, by = blockIdx.y * 32;
    #pragma unroll
    for (int j = 0; j < 4; j++)
        tS[y + j * 8][x] = in[(long)(by + y + j * 8) * HID_ + bx + x];
    __syncthreads();
    #pragma unroll
    for (int j = 0; j < 4; j++)
        out[(long)(bx + y + j * 8) * HID_ + by + x] = f2bf(tS[x][y + j * 8]);
}

// ---------------- bf16 MFMA GEMM 128x128: Y = A(MxK) @ Bt^T, Bt = [N][K] ----------------
// Used for QKV: bf16 out split q/k/v by gn>>10; RoPE fused in epilogue; q scaled
// by 0.125*log2e (attention runs softmax in log2 domain).
__global__ __launch_bounds__(256, 3) void gemm_qkv(const u16* __restrict__ A,
                                                   const u16* __restrict__ Bt,
                                                   u16* __restrict__ outb,
                                                   const float* __restrict__ cosb,
                                                   const float* __restrict__ sinb,
                                                   int K) {
    __shared__ u16 As[128 * 32];
    __shared__ u16 Bs[128 * 32];
    const int t = threadIdx.x;
    const int lane = t & 63;
    const int w = t >> 6;
    const int qlane = lane & 15, grp = lane >> 4;
    const int m0 = blockIdx.y * 128, n0 = blockIdx.x * 128;
    const int wr = w >> 1, wc = w & 1;

    f32x4 acc[4][4];
    #pragma unroll
    for (int i = 0; i < 4; i++)
        #pragma unroll
        for (int j = 0; j < 4; j++) acc[i][j] = (f32x4){0.f, 0.f, 0.f, 0.f};

    const int srow = (lane >> 2);
    const int scol = (lane & 3) * 8;
    const int nkt = K >> 5;
    for (int kt = 0; kt < nkt; kt++) {
        const int k0 = kt << 5;
        #pragma unroll
        for (int c = 0; c < 2; c++) {
            const int chunk = w * 2 + c;
            const int row = chunk * 16 + srow;
            gll16(A  + (long)(m0 + row) * K + k0 + scol, As + chunk * 512);
            gll16(Bt + (long)(n0 + row) * K + k0 + scol, Bs + chunk * 512);
        }
        __syncthreads();
        bf16x8 af[4], bfr[4];
        #pragma unroll
        for (int i = 0; i < 4; i++) {
            af[i]  = *(const bf16x8*)(As + (wr * 64 + i * 16 + qlane) * 32 + grp * 8);
            bfr[i] = *(const bf16x8*)(Bs + (wc * 64 + i * 16 + qlane) * 32 + grp * 8);
        }
        #pragma unroll
        for (int mf = 0; mf < 4; mf++)
            #pragma unroll
            for (int nf = 0; nf < 4; nf++)
                acc[mf][nf] = __builtin_amdgcn_mfma_f32_16x16x32_bf16(af[mf], bfr[nf], acc[mf][nf], 0, 0, 0);
        __syncthreads();
    }

    const int gnb = n0 + wc * 64;     // head-aligned 64-col half
    #pragma unroll
    for (int mf = 0; mf < 4; mf++) {
        #pragma unroll
        for (int r = 0; r < 4; r++) {
            const int m = m0 + wr * 64 + mf * 16 + grp * 4 + r;
            float a0 = acc[mf][0][r], a1 = acc[mf][1][r];
            float a2 = acc[mf][2][r], a3 = acc[mf][3][r];
            if (gnb < 2048) {                     // q or k head: RoPE
                const int s = m & (S_ - 1);
                const float* cr = cosb + s * 64;
                const float* sr = sinb + s * 64;
                float c0 = cr[qlane], c1 = cr[qlane + 16], c2 = cr[qlane + 32], c3 = cr[qlane + 48];
                float z0 = sr[qlane], z1 = sr[qlane + 16], z2 = sr[qlane + 32], z3 = sr[qlane + 48];
                float n0v = a0 * c0 - a2 * z0;
                float n1v = a1 * c1 - a3 * z1;
                float n2v = a2 * c2 + a0 * z2;
                float n3v = a3 * c3 + a1 * z3;
                if (gnb < 1024) {                  // q: fold 0.125 * log2e
                    const float QS = 0.125f * LOG2E;
                    n0v *= QS; n1v *= QS; n2v *= QS; n3v *= QS;
                }
                a0 = n0v; a1 = n1v; a2 = n2v; a3 = n3v;
            }
            const float av[4] = {a0, a1, a2, a3};
            #pragma unroll
            for (int nf = 0; nf < 4; nf++) {
                const int gn = gnb + nf * 16 + qlane;
                outb[((long)(gn >> 10)) * ((long)4096 * 1024) + (long)m * 1024 + (gn & 1023)]
                    = f2bf(av[nf]);
            }
        }
    }
}

// ---------------- bf16 MFMA GEMM 128x64 (f32 out) for ctx @ Wo ----------------
// 512 blocks -> 2/CU (the 128x128 version gave 256 blocks = 1 wave/SIMD, latency-exposed).
__global__ __launch_bounds__(256, 3) void gemm_n64(const u16* __restrict__ A,
                                                   const u16* __restrict__ Bt,
                                                   float* __restrict__ outf,
                                                   int K) {
    __shared__ u16 As[128 * 32];
    __shared__ u16 Bs[64 * 32];
    const int t = threadIdx.x;
    const int lane = t & 63;
    const int w = t >> 6;
    const int qlane = lane & 15, grp = lane >> 4;
    const int m0 = blockIdx.y * 128, n0 = blockIdx.x * 64;

    f32x4 acc[2][4];
    #pragma unroll
    for (int i = 0; i < 2; i++)
        #pragma unroll
        for (int j = 0; j < 4; j++) acc[i][j] = (f32x4){0.f, 0.f, 0.f, 0.f};

    const int srow = (lane >> 2);
    const int scol = (lane & 3) * 8;
    const int nkt = K >> 5;
    for (int kt = 0; kt < nkt; kt++) {
        const int k0 = kt << 5;
        #pragma unroll
        for (int c = 0; c < 2; c++) {
            const int chunk = w * 2 + c;
            const int row = chunk * 16 + srow;
            gll16(A + (long)(m0 + row) * K + k0 + scol, As + chunk * 512);
        }
        gll16(Bt + (long)(n0 + w * 16 + srow) * K + k0 + scol, Bs + w * 512);
        __syncthreads();
        bf16x8 af[2], bfr[4];
        #pragma unroll
        for (int i = 0; i < 2; i++)
            af[i] = *(const bf16x8*)(As + (w * 32 + i * 16 + qlane) * 32 + grp * 8);
        #pragma unroll
        for (int i = 0; i < 4; i++)
            bfr[i] = *(const bf16x8*)(Bs + (i * 16 + qlane) * 32 + grp * 8);
        #pragma unroll
        for (int mf = 0; mf < 2; mf++)
            #pragma unroll
            for (int nf = 0; nf < 4; nf++)
                acc[mf][nf] = __builtin_amdgcn_mfma_f32_16x16x32_bf16(af[mf], bfr[nf], acc[mf][nf], 0, 0, 0);
        __syncthreads();
    }

    #pragma unroll
    for (int mf = 0; mf < 2; mf++)
        #pragma unroll
        for (int r = 0; r < 4; r++) {
            const int m = m0 + w * 32 + mf * 16 + grp * 4 + r;
            #pragma unroll
            for (int nf = 0; nf < 4; nf++)
                outf[(long)m * 1024 + n0 + nf * 16 + qlane] = acc[mf][nf][r];
        }
}

// ---------------- MFMA flash attention: 8 waves, 128 q-rows/block ----------------
// Each staged 64x64 K/V tile feeds 8 waves (staging per compute halved vs 4-wave).
// Softmax in log2 domain (q pre-scaled by 0.125*log2e; bias staged *log2e).
// Per-wave runtime modes: skip / far(const bias, no mask) / near(bias) / diag(+mask).
__global__ __launch_bounds__(512, 4) void attn_mfma(const u16* __restrict__ q,
                                                    const u16* __restrict__ k,
                                                    const u16* __restrict__ v,
                                                    const float* __restrict__ rel_bias,
                                                    u16* __restrict__ ctx) {
    __shared__ __align__(16) unsigned char kS[2][8192];   // K [k][d] bf16, swzK
    __shared__ __align__(16) unsigned char vS[2][8192];   // V^T [d][k] bf16, swzV
    __shared__ float bb[2][192];

    const int t    = threadIdx.x;
    const int lane = t & 63;
    const int w    = t >> 6;                     // 0..7
    const int n    = blockIdx.x;                 // 512 blocks
    const int xcd  = n & 7;
    const int hbhi = (n >> 7) & 3;
    int qtb        = (n >> 3) & 15;
    if (hbhi & 2) qtb = 15 - qtb;                // zigzag: CU's 2 blocks sum to 36 tiles
    const int hb   = xcd + (hbhi << 3);          // same xcd-slot -> 4 heads per XCD
    const int h    = hb & 15, b = hb >> 4;
    const int q0   = qtb * 128;
    const int wq   = w * 16;
    const int qlane = lane & 15;
    const int grp   = lane >> 4;

    const long bhbase = ((long)b * S_ * H_ + h) * D_;
    const float bfar  = rel_bias[31 * H_ + h] * LOG2E;   // bucket 31: all rp >= 113

    // staging coords
    const int kr  = t >> 3,        kc  = (t & 7) * 8;    // K: 1 row, 8 cols (b128)
    const int vrb = (t >> 5) * 4,  vcp = (t & 31) * 2;   // V: 4 rows x 2 cols

    bf16x8 qf0, qf1;
    {
        const u16* qrow = q + bhbase + (long)(q0 + wq + qlane) * (H_ * D_);
        qf0 = *(const bf16x8*)(qrow + grp * 8);
        qf1 = *(const bf16x8*)(qrow + 32 + grp * 8);
    }

    f32x4 oacc[4];
    #pragma unroll
    for (int db = 0; db < 4; db++) oacc[db] = (f32x4){0.f, 0.f, 0.f, 0.f};
    float m_run = -1.0e30f, l_run = 0.f;

    bf16x8 kreg;
    unsigned vreg[4];
    float breg = 0.f;

    auto prefetch = [&](int k0, bool needb) {
        kreg = *(const bf16x8*)(k + bhbase + (long)(k0 + kr) * (H_ * D_) + kc);
        const u16* vp = v + bhbase + (long)(k0 + vrb) * (H_ * D_) + vcp;
        #pragma unroll
        for (int i = 0; i < 4; i++)
            vreg[i] = *(const unsigned*)(vp + (long)i * (H_ * D_));
        if (needb && t < 192) {
            int rp = (q0 - 63) + t - k0;
            float bv = 0.f;
            if (rp >= 0) {
                int bucket;
                if (rp < 16) bucket = rp;
                else {
                    int lg = (int)(logf((float)rp * 0.0625f) * 7.69437361f);
                    bucket = 16 + lg;
                    if (bucket > 31) bucket = 31;
                }
                bv = rel_bias[bucket * H_ + h] * LOG2E;
            }
            breg = bv;
        }
    };
    auto writetile = [&](int buf, bool needb) {
        *(bf16x8*)(kS[buf] + swzK(kr, kc * 2)) = kreg;
        ushort2 a0 = __builtin_bit_cast(ushort2, vreg[0]);
        ushort2 a1 = __builtin_bit_cast(ushort2, vreg[1]);
        ushort2 a2 = __builtin_bit_cast(ushort2, vreg[2]);
        ushort2 a3 = __builtin_bit_cast(ushort2, vreg[3]);
        ushort4 d0; d0.x = a0.x; d0.y = a1.x; d0.z = a2.x; d0.w = a3.x;
        ushort4 d1; d1.x = a0.y; d1.y = a1.y; d1.z = a2.y; d1.w = a3.y;
        *(ushort4*)(vS[buf] + swzV(vcp,     vrb * 2)) = d0;
        *(ushort4*)(vS[buf] + swzV(vcp + 1, vrb * 2)) = d1;
        if (needb && t < 192) bb[buf][t] = breg;
    };

    const int NT = 2 * qtb + 2;
    const bool needb0 = (q0 < 176);
    prefetch(0, needb0);
    writetile(0, needb0);
    __syncthreads();

    int cur = 0;
    for (int kt = 0; kt < NT; kt++) {
        const int k0 = kt * 64;
        const bool has_next = (kt + 1) < NT;
        const bool needb_n  = (q0 - (k0 + 64)) < 176;
        if (has_next) prefetch(k0 + 64, needb_n);

        const bool skip = k0 > q0 + wq + 15;
        if (!skip) {
            const bool use_bias = (q0 + wq - k0) < 176;
            const bool is_diag  = (k0 + 63) > (q0 + wq);

            __builtin_amdgcn_s_setprio(1);
            f32x4 sacc[4];
            #pragma unroll
            for (int kb = 0; kb < 4; kb++) {
                sacc[kb] = (f32x4){0.f, 0.f, 0.f, 0.f};
                bf16x8 kf0 = *(const bf16x8*)(kS[cur] + swzK(kb * 16 + qlane, grp * 16));
                bf16x8 kf1 = *(const bf16x8*)(kS[cur] + swzK(kb * 16 + qlane, 64 + grp * 16));
                sacc[kb] = __builtin_amdgcn_mfma_f32_16x16x32_bf16(kf0, qf0, sacc[kb], 0, 0, 0);
                sacc[kb] = __builtin_amdgcn_mfma_f32_16x16x32_bf16(kf1, qf1, sacc[kb], 0, 0, 0);
            }
            __builtin_amdgcn_s_setprio(0);

            float pv_[4][4];
            float tmax = -1.0e30f;
            #pragma unroll
            for (int kb = 0; kb < 4; kb++) {
                #pragma unroll
                for (int r = 0; r < 4; r++) {
                    float s = sacc[kb][r];               // log2 domain
                    if (use_bias) {
                        const int k_l = kb * 16 + grp * 4 + r;
                        s += bb[cur][wq + qlane - k_l + 63];
                        if (is_diag)
                            s = ((k0 + k_l) <= (q0 + wq + qlane)) ? s : -1.0e9f;
                    }
                    pv_[kb][r] = s;
                }
                tmax = fmaxf(tmax,
                       fmaxf(fmaxf(pv_[kb][0], pv_[kb][1]), fmaxf(pv_[kb][2], pv_[kb][3])));
            }
            tmax = fmaxf(tmax, __shfl_xor(tmax, 16));
            tmax = fmaxf(tmax, __shfl_xor(tmax, 32));

            const float bofs = use_bias ? 0.f : bfar;
            const float teff = tmax + bofs;
            float msub;
            if (__all(teff <= m_run + 11.5f)) {          // defer (2^11.5 ~ e^8 headroom)
                msub = m_run - bofs;
            } else {
                float mnew  = fmaxf(m_run, teff);
                float scale = __builtin_amdgcn_exp2f(m_run - mnew);
                l_run *= scale;
                float scl[4];
                #pragma unroll
                for (int r = 0; r < 4; r++) scl[r] = __shfl(scale, grp * 4 + r, 64);
                #pragma unroll
                for (int db = 0; db < 4; db++)
                    #pragma unroll
                    for (int r = 0; r < 4; r++) oacc[db][r] *= scl[r];
                m_run = mnew;
                msub = mnew - bofs;
            }

            float tsum = 0.f;
            #pragma unroll
            for (int kb = 0; kb < 4; kb++)
                #pragma unroll
                for (int r = 0; r < 4; r++) {
                    float p = __builtin_amdgcn_exp2f(pv_[kb][r] - msub);
                    pv_[kb][r] = p;
                    tsum += p;
                }
            tsum += __shfl_xor(tsum, 16);
            tsum += __shfl_xor(tsum, 32);
            l_run += tsum;

            bf16x8 pf[2];
            #pragma unroll
            for (int ks = 0; ks < 2; ks++) {
                unsigned u0 = cvtpk(pv_[2 * ks][0], pv_[2 * ks][1]);
                unsigned u1 = cvtpk(pv_[2 * ks][2], pv_[2 * ks][3]);
                unsigned u2 = cvtpk(pv_[2 * ks + 1][0], pv_[2 * ks + 1][1]);
                unsigned u3 = cvtpk(pv_[2 * ks + 1][2], pv_[2 * ks + 1][3]);
                pf[ks] = __builtin_bit_cast(bf16x8, (uint4v){u0, u1, u2, u3});
            }

            __builtin_amdgcn_s_setprio(1);
            #pragma unroll
            for (int db = 0; db < 4; db++) {
                #pragma unroll
                for (int ks = 0; ks < 2; ks++) {
                    bf16x4 lo = *(const bf16x4*)(vS[cur] + swzV(db * 16 + qlane, ks * 64 + grp * 8));
                    bf16x4 hi = *(const bf16x4*)(vS[cur] + swzV(db * 16 + qlane, ks * 64 + 32 + grp * 8));
                    bf16x8 vf = __builtin_shufflevector(lo, hi, 0, 1, 2, 3, 4, 5, 6, 7);
                    oacc[db] = __builtin_amdgcn_mfma_f32_16x16x32_bf16(pf[ks], vf, oacc[db], 0, 0, 0);
                }
            }
            __builtin_amdgcn_s_setprio(0);
        }

        if (has_next) writetile(cur ^ 1, needb_n);
        __syncthreads();
        cur ^= 1;
    }

    float inv = 1.0f / l_run;
    float invr[4];
    #pragma unroll
    for (int r = 0; r < 4; r++) invr[r] = __shfl(inv, grp * 4 + r, 64);
    #pragma unroll
    for (int r = 0; r < 4; r++) {
        long qg = q0 + wq + grp * 4 + r;
        u16* dst = ctx + (long)(b * S_ + qg) * HID_ + h * D_ + qlane;
        #pragma unroll
        for (int db = 0; db < 4; db++)
            dst[db * 16] = f2bf(oacc[db][r] * invr[r]);
    }
}

extern "C" void kernel_launch(void* const* d_in, const int* in_sizes, int n_in,
                              void* d_out, int out_size, void* d_ws, size_t ws_size,
                              hipStream_t stream) {
    const float* x    = (const float*)d_in[0];
    const float* Wq   = (const float*)d_in[1];
    const float* Wk   = (const float*)d_in[2];
    const float* Wv   = (const float*)d_in[3];
    const float* Wo   = (const float*)d_in[4];
    const float* rb   = (const float*)d_in[5];
    const float* cosb = (const float*)d_in[6];
    const float* sinb = (const float*)d_in[7];
    float* out = (float*)d_out;

    char* wsb = (char*)d_ws;
    u16* xb    = (u16*)(wsb);
    u16* wqkvT = (u16*)(wsb + (8L  << 20));
    u16* woT   = (u16*)(wsb + (14L << 20));
    u16* qb    = (u16*)(wsb + (16L << 20));
    u16* kb    = (u16*)(wsb + (24L << 20));
    u16* vb    = (u16*)(wsb + (32L << 20));
    u16* ctxb  = (u16*)(wsb + (40L << 20));

    hipLaunchKernelGGL(convert_x, dim3((B_ * S_ * HID_ / 4) / 256), dim3(256), 0, stream, x, xb);
    hipLaunchKernelGGL(transpose_w4, dim3(32, 32, 4), dim3(32, 8), 0, stream,
                       Wq, Wk, Wv, Wo,
                       wqkvT, wqkvT + (1L << 20), wqkvT + (2L << 20), woT);

    hipLaunchKernelGGL(gemm_qkv, dim3(24, 32), dim3(256), 0, stream,
                       xb, wqkvT, qb, cosb, sinb, HID_);
    hipLaunchKernelGGL(attn_mfma, dim3(512), dim3(512), 0, stream,
                       qb, kb, vb, rb, ctxb);
    hipLaunchKernelGGL(gemm_n64, dim3(16, 32), dim3(256), 0, stream,
                       ctxb, woT, out, HID_);
}